// Round 8
// baseline (6585.457 us; speedup 1.0000x reference)
//
#include <hip/hip_runtime.h>

// Seq2Seq LSTM (B=64, S=T=256, DIN=DOUT=128, H=1024).
// Round 8: persistent kernel with a WRITE-ONCE h-buffer chain (hseq[0..511])
// -> no address is ever re-read after being re-written -> stale cache lines
// cannot exist -> ZERO acquire/release/invalidate in the whole loop.
//   - h stores: relaxed agent u32 atomics (MALL-direct, never dirty L2).
//   - h loads:  plain cached dwordx4 (cold L2 miss -> MALL -> fresh).
//   - weights/srcp: plain cached, L2-hot forever (never invalidated).
//   - barrier: flat slot-per-block array; arrival = 1 relaxed agent store;
//     detect = threads t<256 poll one slot each in parallel. Monotonic,
//     re-zeroed by init each launch (graph-safe).
// hist is merged into hseq (decoder h_t = hseq[257+t-1]); fc_batch reads it.
// Weights per-phase in registers; c-state in registers. Split-bf16 (3 MFMA).

#define BB   64
#define HH   1024
#define G4   4096
#define DXX  128
#define KC   128
#define SEQN 256
#define TN   256
#define OUT_BSTRIDE (TN * DXX)

#define HROW 2048                 // h row: [h_hi 1024][h_lo 1024]
#define SLOT (64 * HROW)          // one h buffer: 131072 halves = 256 KB

typedef __attribute__((ext_vector_type(8))) short short8;
typedef __attribute__((ext_vector_type(4))) float f32x4;

__device__ __forceinline__ float sigm(float x)  { return 1.f / (1.f + __expf(-x)); }
__device__ __forceinline__ float tanh_f(float x){ return 1.f - 2.f / (1.f + __expf(2.f * x)); }

__device__ __forceinline__ unsigned short bf16_rn(float x) {
    union { float f; unsigned u; } v; v.f = x;
    unsigned r = v.u + 0x7fffu + ((v.u >> 16) & 1u);
    return (unsigned short)(r >> 16);
}
__device__ __forceinline__ float bf16f(unsigned short h) {
    union { unsigned u; float f; } v; v.u = ((unsigned)h) << 16; return v.f;
}

// ================= persistent step =================
// KT=9 (+XPART: kw==3,kt>=5 read x from xs) or KT=8 (pure h).
template<int KT, bool XPART>
__device__ __forceinline__ void do_step(
    const short8 (&w)[9][2],
    const unsigned short* __restrict__ A,    // hseq[s]   (read, cached)
    unsigned short* __restrict__ An,         // hseq[s+1] (write, MALL)
    float* red, int mrow, int kl, int kw, int rbase,
    int t, int b, int nl, int nh, const float (&bb)[4], float& creg,
    const unsigned short* __restrict__ xs,   // [64][256] hi|lo (immutable) or null
    unsigned* __restrict__ bar, unsigned step)
{
    f32x4 acc = {0.f, 0.f, 0.f, 0.f};
    const unsigned short* Ar = A + mrow * HROW;
    #pragma unroll
    for (int kt = 0; kt < KT; ++kt) {
        const int kg = kw * (KT * 32) + kt * 32 + kl;
        short8 ah, al;
        if (XPART && kw == 3 && kt >= 5) {
            const int xo = mrow * 256 + (kg - 1024);
            ah = *(const short8*)(xs + xo);
            al = *(const short8*)(xs + xo + 128);
        } else {
            ah = *(const short8*)(Ar + kg);          // cached, cold-miss -> MALL
            al = *(const short8*)(Ar + 1024 + kg);
        }
        acc = __builtin_amdgcn_mfma_f32_16x16x32_bf16(ah, w[kt][0], acc, 0, 0, 0);
        acc = __builtin_amdgcn_mfma_f32_16x16x32_bf16(ah, w[kt][1], acc, 0, 0, 0);
        acc = __builtin_amdgcn_mfma_f32_16x16x32_bf16(al, w[kt][0], acc, 0, 0, 0);
    }
    #pragma unroll
    for (int r = 0; r < 4; ++r) red[rbase + r * 17] = acc[r];
    __syncthreads();

    if (t < 256) {
        float g4[4];
        #pragma unroll
        for (int gt = 0; gt < 4; ++gt) {
            const int cc = nl * 4 + gt;
            g4[gt] = red[b * 17 + cc] + red[(64 + b) * 17 + cc]
                   + red[(128 + b) * 17 + cc] + red[(192 + b) * 17 + cc] + bb[gt];
        }
        const float cv = sigm(g4[1]) * creg + sigm(g4[0]) * tanh_f(g4[2]);
        creg = cv;
        const float hv = sigm(g4[3]) * tanh_f(cv);
        const unsigned short hh = bf16_rn(hv);
        const unsigned short hl = bf16_rn(hv - bf16f(hh));
        // pair (nl even | nl odd) into one u32 MALL store each for hi and lo
        const unsigned phh = (unsigned)__shfl_xor((int)(unsigned)hh, 1);
        const unsigned phl = (unsigned)__shfl_xor((int)(unsigned)hl, 1);
        if ((nl & 1) == 0) {
            const unsigned wh = (unsigned)hh | (phh << 16);
            const unsigned wl = (unsigned)hl | (phl << 16);
            __hip_atomic_store((unsigned*)(An + b * HROW + nh), wh,
                               __ATOMIC_RELAXED, __HIP_MEMORY_SCOPE_AGENT);
            __hip_atomic_store((unsigned*)(An + b * HROW + 1024 + nh), wl,
                               __ATOMIC_RELAXED, __HIP_MEMORY_SCOPE_AGENT);
        }
    }
    // -------- device barrier: flat slots, all relaxed, no cache ops --------
    __syncthreads();   // per-wave vmcnt drain: all MALL stores above are acked
    if (t == 0)
        __hip_atomic_store(bar + blockIdx.x, step,
                           __ATOMIC_RELAXED, __HIP_MEMORY_SCOPE_AGENT);
    if (t < 256) {
        while (__hip_atomic_load(bar + t, __ATOMIC_RELAXED,
                                 __HIP_MEMORY_SCOPE_AGENT) < step)
            __builtin_amdgcn_s_sleep(1);
    }
    __syncthreads();
}

__global__ __launch_bounds__(1024, 1)
void persist(const unsigned short* __restrict__ Wencf,
             const unsigned short* __restrict__ Wdec0f,
             const unsigned short* __restrict__ Wcombf,
             const unsigned short* __restrict__ srcp,
             const unsigned short* __restrict__ trgp,
             const float* __restrict__ benc,
             const float* __restrict__ bdec0,
             const float* __restrict__ bcomb,
             unsigned short* __restrict__ hseq,   // [512][64][2048]
             unsigned* __restrict__ bar)
{
    __shared__ float red[4 * 64 * 17];
    const int t  = threadIdx.x;
    const int bi = blockIdx.x;
    const int l  = t & 63;
    const int wv = t >> 6;
    const int mw = wv & 3;
    const int kw = wv >> 2;
    const int lm = l & 15;
    const int kl = (l >> 4) << 3;
    const int mrow = mw * 16 + lm;
    const int rbase = (kw * 64 + mw * 16 + (l >> 4) * 4) * 17 + lm;
    const int b  = t >> 2;
    const int nl = t & 3;
    const int nh = bi * 4 + nl;

    short8 w[9][2];
    float bb[4];
    float creg = 0.f;
    unsigned step = 0;

    // ---- encoder phase: steps 0..255, hseq[s] -> hseq[s+1] ----
    {
        const unsigned short* wp = Wencf + ((size_t)(bi * 4 + kw) * 9) * 1024 + l * 8;
        #pragma unroll
        for (int kt = 0; kt < 9; ++kt) {
            w[kt][0] = *(const short8*)(wp + kt * 1024);
            w[kt][1] = *(const short8*)(wp + kt * 1024 + 512);
        }
    }
    if (t < 256) {
        #pragma unroll
        for (int g = 0; g < 4; ++g) bb[g] = benc[bi * 16 + nl * 4 + g];
    }
    for (int s = 0; s < 256; ++s) {
        ++step;
        do_step<9, true>(w, hseq + (size_t)s * SLOT, hseq + (size_t)(s + 1) * SLOT,
                         red, mrow, kl, kw, rbase, t, b, nl, nh, bb, creg,
                         srcp + (size_t)s * 16384, bar, step);
    }
    // ---- decoder step 0 (input = trg[:,0,:]): step 256 -> hseq[257] = h_1 ----
    {
        const unsigned short* wp = Wdec0f + ((size_t)(bi * 4 + kw) * 9) * 1024 + l * 8;
        #pragma unroll
        for (int kt = 0; kt < 9; ++kt) {
            w[kt][0] = *(const short8*)(wp + kt * 1024);
            w[kt][1] = *(const short8*)(wp + kt * 1024 + 512);
        }
    }
    if (t < 256) {
        #pragma unroll
        for (int g = 0; g < 4; ++g) bb[g] = bdec0[bi * 16 + nl * 4 + g];
    }
    ++step;
    do_step<9, true>(w, hseq + (size_t)256 * SLOT, hseq + (size_t)257 * SLOT,
                     red, mrow, kl, kw, rbase, t, b, nl, nh, bb, creg,
                     trgp, bar, step);
    // ---- decoder comb phase: steps 257..510 -> hseq[258..511] = h_2..h_255 ----
    {
        const unsigned short* wp = Wcombf + ((size_t)(bi * 4 + kw) * 8) * 1024 + l * 8;
        #pragma unroll
        for (int kt = 0; kt < 8; ++kt) {
            w[kt][0] = *(const short8*)(wp + kt * 1024);
            w[kt][1] = *(const short8*)(wp + kt * 1024 + 512);
        }
    }
    if (t < 256) {
        #pragma unroll
        for (int g = 0; g < 4; ++g) bb[g] = bcomb[bi * 16 + nl * 4 + g];
    }
    for (int s = 257; s < 511; ++s) {
        ++step;
        do_step<8, false>(w, hseq + (size_t)s * SLOT, hseq + (size_t)(s + 1) * SLOT,
                          red, mrow, kl, kw, rbase, t, b, nl, nh, bb, creg,
                          nullptr, bar, step);
    }
}

// ================= batched FC over hseq[257..511] =================
// block bi (0..254): out[:, bi+1, :] = hseq[257+bi] @ fcW^T + fcb
__global__ __launch_bounds__(256)
void fc_batch(const unsigned short* __restrict__ fcf,   // [256 frags][1024]
              const unsigned short* __restrict__ hseq,
              const float* __restrict__ fcb,
              float* __restrict__ out)
{
    const int t = threadIdx.x, bi = blockIdx.x;
    const int l = t & 63, wv = t >> 6;
    const int lm = l & 15, kl = (l >> 4) << 3;
    const int mrow = wv * 16 + lm;
    const unsigned short* Ar = hseq + (size_t)(257 + bi) * SLOT + mrow * HROW;

    f32x4 acc[8];
    #pragma unroll
    for (int nt = 0; nt < 8; ++nt) acc[nt] = f32x4{0.f, 0.f, 0.f, 0.f};

    for (int kt = 0; kt < 32; ++kt) {
        const short8 ah = *(const short8*)(Ar + kt * 32 + kl);
        const short8 al = *(const short8*)(Ar + 1024 + kt * 32 + kl);
        #pragma unroll
        for (int nt = 0; nt < 8; ++nt) {
            const unsigned short* bp = fcf + (size_t)(nt * 32 + kt) * 1024 + l * 8;
            const short8 bh = *(const short8*)bp;
            const short8 bl = *(const short8*)(bp + 512);
            acc[nt] = __builtin_amdgcn_mfma_f32_16x16x32_bf16(ah, bh, acc[nt], 0, 0, 0);
            acc[nt] = __builtin_amdgcn_mfma_f32_16x16x32_bf16(ah, bl, acc[nt], 0, 0, 0);
            acc[nt] = __builtin_amdgcn_mfma_f32_16x16x32_bf16(al, bh, acc[nt], 0, 0, 0);
        }
    }
    #pragma unroll
    for (int nt = 0; nt < 8; ++nt) {
        const float bv = fcb[nt * 16 + lm];
        #pragma unroll
        for (int r = 0; r < 4; ++r) {
            const int bq = wv * 16 + (l >> 4) * 4 + r;
            out[(size_t)bq * OUT_BSTRIDE + (size_t)(bi + 1) * DXX + nt * 16 + lm] = acc[nt][r] + bv;
        }
    }
}

// ================= prep kernels =================
__global__ __launch_bounds__(256)
void prep_frag_12(const float* __restrict__ Whh, const float* __restrict__ Wih,
                  unsigned short* __restrict__ dst)   // KT=9, K=1152 [Whh|Wih]
{
    const int idx = blockIdx.x * 256 + threadIdx.x;   // 0..589823
    const int l = idx & 63;
    const int fid = idx >> 6;
    const int kt = fid % 9;
    const int rem = fid / 9;
    const int kw = rem & 3;
    const int biq = rem >> 2;
    const int col = biq * 16 + (l & 15);
    const int hid = col >> 2, g = col & 3;
    const int k0 = kw * 288 + kt * 32 + ((l >> 4) << 3);
    short8 vh, vl;
    #pragma unroll
    for (int e = 0; e < 8; ++e) {
        const int k = k0 + e;
        const float wv = (k < 1024) ? Whh[(size_t)(g * 1024 + hid) * 1024 + k]
                                    : Wih[(size_t)(g * 1024 + hid) * 128 + (k - 1024)];
        const unsigned short hi = bf16_rn(wv);
        vh[e] = (short)hi;
        vl[e] = (short)bf16_rn(wv - bf16f(hi));
    }
    *(short8*)(dst + (size_t)fid * 1024 + l * 8) = vh;
    *(short8*)(dst + (size_t)fid * 1024 + 512 + l * 8) = vl;
}

__global__ __launch_bounds__(256)
void prep_frag_comb(const float* __restrict__ Wc, unsigned short* __restrict__ dst)
{
    const int idx = blockIdx.x * 256 + threadIdx.x;   // 0..524287
    const int l = idx & 63;
    const int fid = idx >> 6;
    const int kt = fid & 7;
    const int rem = fid >> 3;
    const int kw = rem & 3;
    const int biq = rem >> 2;
    const int col = biq * 16 + (l & 15);
    const int hid = col >> 2, g = col & 3;
    const int k0 = kw * 256 + kt * 32 + ((l >> 4) << 3);
    short8 vh, vl;
    #pragma unroll
    for (int e = 0; e < 8; ++e) {
        const float wv = Wc[(size_t)(g * 1024 + hid) * 1024 + k0 + e];
        const unsigned short hi = bf16_rn(wv);
        vh[e] = (short)hi;
        vl[e] = (short)bf16_rn(wv - bf16f(hi));
    }
    *(short8*)(dst + (size_t)fid * 1024 + l * 8) = vh;
    *(short8*)(dst + (size_t)fid * 1024 + 512 + l * 8) = vl;
}

__global__ __launch_bounds__(256)
void prep_frag_fc(const float* __restrict__ fcW, unsigned short* __restrict__ dst)
{
    const int idx = blockIdx.x * 256 + threadIdx.x;   // 0..16383
    const int l = idx & 63;
    const int fid = idx >> 6;                          // nt*32 + kt
    const int nt = fid >> 5, kt = fid & 31;
    const int col = nt * 16 + (l & 15);
    const int k0 = kt * 32 + ((l >> 4) << 3);
    short8 vh, vl;
    #pragma unroll
    for (int e = 0; e < 8; ++e) {
        const float wv = fcW[(size_t)col * 1024 + k0 + e];
        const unsigned short hi = bf16_rn(wv);
        vh[e] = (short)hi;
        vl[e] = (short)bf16_rn(wv - bf16f(hi));
    }
    *(short8*)(dst + (size_t)fid * 1024 + l * 8) = vh;
    *(short8*)(dst + (size_t)fid * 1024 + 512 + l * 8) = vl;
}

__global__ __launch_bounds__(256)
void prep_bias_p(const float* __restrict__ ebi, const float* __restrict__ ebh,
                 const float* __restrict__ dbi, const float* __restrict__ dbh,
                 const float* __restrict__ dWih, const float* __restrict__ fcb,
                 float* __restrict__ benc, float* __restrict__ bdec0,
                 float* __restrict__ bcomb)
{
    const int idx = blockIdx.x * 256 + threadIdx.x;   // grid 16 -> 4096
    const int orig = ((idx & 3) << 10) | (idx >> 2);
    benc[idx] = ebi[orig] + ebh[orig];
    const float db = dbi[orig] + dbh[orig];
    bdec0[idx] = db;
    float a = db;
    const float* wr = dWih + (size_t)orig * DXX;
    for (int d = 0; d < DXX; ++d) a += wr[d] * fcb[d];
    bcomb[idx] = a;
}

__global__ __launch_bounds__(256)
void prep_src(const float* __restrict__ src, unsigned short* __restrict__ so, int n)
{
    const int idx = blockIdx.x * 256 + threadIdx.x;
    if (idx < n) {
        const int b = idx >> 15, s = (idx >> 7) & 255, d = idx & 127;
        const float v = src[idx];
        const unsigned short hi = bf16_rn(v);
        unsigned short* dst = so + ((size_t)s * 64 + b) * 256 + d;
        dst[0]   = hi;
        dst[128] = bf16_rn(v - bf16f(hi));
    }
}

__global__ __launch_bounds__(256)
void prep_trg0(const float* __restrict__ trg, unsigned short* __restrict__ tp)
{
    const int idx = blockIdx.x * 256 + threadIdx.x;   // grid 32 -> 8192
    const int bq = idx >> 7, d = idx & 127;
    const float v = trg[(size_t)bq * TN * DXX + d];
    const unsigned short hi = bf16_rn(v);
    tp[bq * 256 + d] = hi;
    tp[bq * 256 + 128 + d] = bf16_rn(v - bf16f(hi));
}

__global__ __launch_bounds__(256)
void init_persist(unsigned short* __restrict__ hseq, float* __restrict__ out,
                  unsigned* __restrict__ bar)
{
    const int idx = blockIdx.x * 256 + threadIdx.x;   // grid 289 -> 73984
    if (idx < SLOT / 2) {                              // zero hseq[0] as u32
        ((unsigned*)hseq)[idx] = 0u;
    } else if (idx < SLOT / 2 + BB * DXX) {
        const int r = idx - SLOT / 2;
        out[(size_t)(r >> 7) * OUT_BSTRIDE + (r & 127)] = 0.f;
    } else if (idx < SLOT / 2 + BB * DXX + 256) {
        // barrier slots: MALL-direct zeros (pollers read MALL)
        __hip_atomic_store(bar + (idx - (SLOT / 2 + BB * DXX)), 0u,
                           __ATOMIC_RELAXED, __HIP_MEMORY_SCOPE_AGENT);
    }
}

// ================= fp32 fallback (round-1 path) =================
__global__ __launch_bounds__(256)
void step_kernel(const float* __restrict__ W, const float* __restrict__ Wx,
                 const float* __restrict__ x, int xstride,
                 const float* __restrict__ bias,
                 const float* __restrict__ h_in, float* __restrict__ c,
                 float* __restrict__ h_out, int nGates,
                 const float* __restrict__ fcW, const float* __restrict__ fcb,
                 float* __restrict__ fc_out, float* __restrict__ predbuf)
{
    __shared__ float hT[KC][BB + 1];
    __shared__ float wl[16][KC];
    const int t   = threadIdx.x;
    const int b   = t & 63;
    const int q   = t >> 6;
    const int col = t & (KC - 1);
    const int r0  = t >> 7;
    const int bi  = blockIdx.x;

    if (bi < nGates) {
        const int n0 = bi * 4;
        const int n  = n0 + q;
        float a0 = bias[n], a1 = bias[HH + n], a2 = bias[2 * HH + n], a3 = bias[3 * HH + n];
        for (int k0 = 0; k0 < HH; k0 += KC) {
            #pragma unroll
            for (int rr = 0; rr < BB; rr += 2)
                hT[col][rr + r0] = h_in[(rr + r0) * HH + k0 + col];
            #pragma unroll
            for (int rr = 0; rr < 16; rr += 2) {
                const int r = rr + r0;
                const int j = (r & 3) * HH + n0 + (r >> 2);
                wl[r][col] = W[(size_t)j * HH + k0 + col];
            }
            __syncthreads();
            #pragma unroll 8
            for (int k = 0; k < KC; k += 4) {
                const float4 w0 = *reinterpret_cast<const float4*>(&wl[q * 4 + 0][k]);
                const float4 w1 = *reinterpret_cast<const float4*>(&wl[q * 4 + 1][k]);
                const float4 w2 = *reinterpret_cast<const float4*>(&wl[q * 4 + 2][k]);
                const float4 w3 = *reinterpret_cast<const float4*>(&wl[q * 4 + 3][k]);
                const float h0v = hT[k][b], h1v = hT[k + 1][b];
                const float h2v = hT[k + 2][b], h3v = hT[k + 3][b];
                a0 += h0v * w0.x + h1v * w0.y + h2v * w0.z + h3v * w0.w;
                a1 += h0v * w1.x + h1v * w1.y + h2v * w1.z + h3v * w1.w;
                a2 += h0v * w2.x + h1v * w2.y + h2v * w2.z + h3v * w2.w;
                a3 += h0v * w3.x + h1v * w3.y + h2v * w3.z + h3v * w3.w;
            }
            __syncthreads();
        }
        if (Wx != nullptr) {
            #pragma unroll
            for (int rr = 0; rr < BB; rr += 2)
                hT[col][rr + r0] = x[(size_t)(rr + r0) * xstride + col];
            #pragma unroll
            for (int rr = 0; rr < 16; rr += 2) {
                const int r = rr + r0;
                const int j = (r & 3) * HH + n0 + (r >> 2);
                wl[r][col] = Wx[(size_t)j * DXX + col];
            }
            __syncthreads();
            #pragma unroll 8
            for (int k = 0; k < DXX; k += 4) {
                const float4 w0 = *reinterpret_cast<const float4*>(&wl[q * 4 + 0][k]);
                const float4 w1 = *reinterpret_cast<const float4*>(&wl[q * 4 + 1][k]);
                const float4 w2 = *reinterpret_cast<const float4*>(&wl[q * 4 + 2][k]);
                const float4 w3 = *reinterpret_cast<const float4*>(&wl[q * 4 + 3][k]);
                const float h0v = hT[k][b], h1v = hT[k + 1][b];
                const float h2v = hT[k + 2][b], h3v = hT[k + 3][b];
                a0 += h0v * w0.x + h1v * w0.y + h2v * w0.z + h3v * w0.w;
                a1 += h0v * w1.x + h1v * w1.y + h2v * w1.z + h3v * w1.w;
                a2 += h0v * w2.x + h1v * w2.y + h2v * w2.z + h3v * w2.w;
                a3 += h0v * w3.x + h1v * w3.y + h2v * w3.z + h3v * w3.w;
            }
        }
        const int ci = b * HH + n;
        const float cv = sigm(a1) * c[ci] + sigm(a0) * tanh_f(a2);
        c[ci] = cv;
        h_out[ci] = sigm(a3) * tanh_f(cv);
    } else if (fcW != nullptr && bi < nGates + 32) {
        const int d0 = (bi - nGates) * 4;
        float a = 0.f;
        for (int k0 = 0; k0 < HH; k0 += KC) {
            #pragma unroll
            for (int rr = 0; rr < BB; rr += 2)
                hT[col][rr + r0] = h_in[(rr + r0) * HH + k0 + col];
            #pragma unroll
            for (int rr = 0; rr < 4; rr += 2)
                wl[rr + r0][col] = fcW[(size_t)(d0 + rr + r0) * HH + k0 + col];
            __syncthreads();
            #pragma unroll 8
            for (int k = 0; k < KC; k += 4) {
                const float4 w0 = *reinterpret_cast<const float4*>(&wl[q][k]);
                const float h0v = hT[k][b], h1v = hT[k + 1][b];
                const float h2v = hT[k + 2][b], h3v = hT[k + 3][b];
                a += h0v * w0.x + h1v * w0.y + h2v * w0.z + h3v * w0.w;
            }
            __syncthreads();
        }
        const int d = d0 + q;
        a += fcb[d];
        if (fc_out)  fc_out[(size_t)b * OUT_BSTRIDE + d] = a;
        if (predbuf) predbuf[b * DXX + d] = a;
    }
}

__global__ __launch_bounds__(256)
void bias_prep(const float* __restrict__ ebi, const float* __restrict__ ebh,
               const float* __restrict__ dbi, const float* __restrict__ dbh,
               const float* __restrict__ dWih, const float* __restrict__ fcbv,
               float* __restrict__ enc_b, float* __restrict__ dec_b, float* __restrict__ bcomb)
{
    __shared__ float fb[DXX];
    const int t = threadIdx.x;
    const int j = blockIdx.x * 256 + t;
    if (t < DXX) fb[t] = fcbv[t];
    __syncthreads();
    enc_b[j] = ebi[j] + ebh[j];
    const float db = dbi[j] + dbh[j];
    dec_b[j] = db;
    float acc = db;
    const float* wr = dWih + (size_t)j * DXX;
    for (int d = 0; d < DXX; d += 4) {
        const float4 w = *reinterpret_cast<const float4*>(&wr[d]);
        acc += w.x * fb[d] + w.y * fb[d + 1] + w.z * fb[d + 2] + w.w * fb[d + 3];
    }
    bcomb[j] = acc;
}

__global__ __launch_bounds__(256)
void wcomb_kernel(const float* __restrict__ dWhh, const float* __restrict__ dWih,
                  const float* __restrict__ fcW, float* __restrict__ Wcomb)
{
    const int bi = blockIdx.x;
    const int j0 = (bi >> 2) * 8;
    const int n  = (bi & 3) * 256 + threadIdx.x;
    __shared__ float wih[8][DXX];
    for (int i = threadIdx.x; i < 8 * DXX; i += 256)
        wih[i >> 7][i & 127] = dWih[(size_t)(j0 + (i >> 7)) * DXX + (i & 127)];
    __syncthreads();
    float acc[8];
    #pragma unroll
    for (int jj = 0; jj < 8; ++jj) acc[jj] = dWhh[(size_t)(j0 + jj) * HH + n];
    for (int d = 0; d < DXX; ++d) {
        const float fv = fcW[(size_t)d * HH + n];
        #pragma unroll
        for (int jj = 0; jj < 8; ++jj) acc[jj] += wih[jj][d] * fv;
    }
    #pragma unroll
    for (int jj = 0; jj < 8; ++jj) Wcomb[(size_t)(j0 + jj) * HH + n] = acc[jj];
}

__global__ __launch_bounds__(256)
void init_kernel(float* __restrict__ h0, float* __restrict__ c, float* __restrict__ out)
{
    const int idx = blockIdx.x * 256 + threadIdx.x;
    if (idx < BB * HH) h0[idx] = 0.f;
    else if (idx < 2 * BB * HH) c[idx - BB * HH] = 0.f;
    else {
        const int r = idx - 2 * BB * HH;
        if (r < BB * DXX) out[(size_t)(r >> 7) * OUT_BSTRIDE + (r & 127)] = 0.f;
    }
}

// ================= host =================
extern "C" void kernel_launch(void* const* d_in, const int* in_sizes, int n_in,
                              void* d_out, int out_size, void* d_ws, size_t ws_size,
                              hipStream_t stream) {
    const float* src   = (const float*)d_in[0];
    const float* trg   = (const float*)d_in[1];
    const float* eWih  = (const float*)d_in[2];
    const float* eWhh  = (const float*)d_in[3];
    const float* ebih  = (const float*)d_in[4];
    const float* ebhh  = (const float*)d_in[5];
    const float* dWih  = (const float*)d_in[6];
    const float* dWhh  = (const float*)d_in[7];
    const float* dbih  = (const float*)d_in[8];
    const float* dbhh  = (const float*)d_in[9];
    const float* fcW   = (const float*)d_in[10];
    const float* fcb   = (const float*)d_in[11];
    float* out = (float*)d_out;

    uintptr_t base = (uintptr_t)d_ws;
    size_t off = 0;
    auto alloc = [&](size_t bytes) -> void* {
        void* p = (void*)(base + off);
        off = (off + bytes + 255) & ~(size_t)255;
        return p;
    };
    unsigned* bar = (unsigned*)alloc(4096);
    unsigned short* srcp = (unsigned short*)alloc((size_t)SEQN * 64 * 256 * 2);
    unsigned short* trgp = (unsigned short*)alloc((size_t)64 * 256 * 2);
    float* benc  = (float*)alloc(G4 * 4);
    float* bdec0 = (float*)alloc(G4 * 4);
    float* bcomb = (float*)alloc(G4 * 4);
    unsigned short* fcf    = (unsigned short*)alloc((size_t)256 * 1024 * 2);
    unsigned short* Wencf  = (unsigned short*)alloc((size_t)9216 * 1024 * 2);
    unsigned short* Wdec0f = (unsigned short*)alloc((size_t)9216 * 1024 * 2);
    unsigned short* Wcombf = (unsigned short*)alloc((size_t)8192 * 1024 * 2);
    float* Wcomb32 = (float*)alloc((size_t)G4 * HH * 4);
    unsigned short* hseq   = (unsigned short*)alloc((size_t)512 * SLOT * 2);
    const bool fastok = (off <= ws_size);

    if (fastok) {
        init_persist<<<289, 256, 0, stream>>>(hseq, out, bar);
        prep_src<<<8192, 256, 0, stream>>>(src, srcp, BB * SEQN * DXX);
        prep_trg0<<<32, 256, 0, stream>>>(trg, trgp);
        prep_bias_p<<<16, 256, 0, stream>>>(ebih, ebhh, dbih, dbhh, dWih, fcb,
                                            benc, bdec0, bcomb);
        prep_frag_12<<<2304, 256, 0, stream>>>(eWhh, eWih, Wencf);
        prep_frag_12<<<2304, 256, 0, stream>>>(dWhh, dWih, Wdec0f);
        wcomb_kernel<<<2048, 256, 0, stream>>>(dWhh, dWih, fcW, Wcomb32);
        prep_frag_comb<<<2048, 256, 0, stream>>>(Wcomb32, Wcombf);
        prep_frag_fc<<<64, 256, 0, stream>>>(fcW, fcf);

        persist<<<256, 1024, 0, stream>>>(Wencf, Wdec0f, Wcombf, srcp, trgp,
                                          benc, bdec0, bcomb, hseq, bar);
        fc_batch<<<255, 256, 0, stream>>>(fcf, hseq, fcb, out);
        return;
    }

    // ---- fallback: fp32 per-step path ----
    float* ws  = (float*)d_ws;
    float* h0     = ws;
    float* h1     = ws + 65536;
    float* cF     = ws + 131072;
    float* pred   = ws + 196608;
    float* enc_b  = ws + 204800;
    float* dec_b  = ws + 208896;
    float* bcombF = ws + 212992;
    float* Wcomb  = ws + 217088;
    const bool use_comb = ws_size >= (size_t)(217088 + 4096 * 1024) * sizeof(float);

    init_kernel<<<544, 256, 0, stream>>>(h0, cF, out);
    bias_prep<<<16, 256, 0, stream>>>(ebih, ebhh, dbih, dbhh, dWih, fcb, enc_b, dec_b, bcombF);
    if (use_comb)
        wcomb_kernel<<<2048, 256, 0, stream>>>(dWhh, dWih, fcW, Wcomb);

    float* hc = h0;
    float* hn = h1;
    for (int s = 0; s < SEQN; ++s) {
        step_kernel<<<256, 256, 0, stream>>>(eWhh, eWih, src + s * DXX, SEQN * DXX,
                                             enc_b, hc, cF, hn, 256,
                                             nullptr, nullptr, nullptr, nullptr);
        float* tmp = hc; hc = hn; hn = tmp;
    }
    step_kernel<<<256, 256, 0, stream>>>(dWhh, dWih, trg, TN * DXX,
                                         dec_b, hc, cF, hn, 256,
                                         nullptr, nullptr, nullptr, nullptr);
    { float* tmp = hc; hc = hn; hn = tmp; }
    if (use_comb) {
        for (int tt = 1; tt <= TN - 2; ++tt) {
            step_kernel<<<288, 256, 0, stream>>>(Wcomb, nullptr, nullptr, 0,
                                                 bcombF, hc, cF, hn, 256,
                                                 fcW, fcb, out + (size_t)tt * DXX, nullptr);
            float* tmp = hc; hc = hn; hn = tmp;
        }
    } else {
        for (int tt = 1; tt <= TN - 2; ++tt) {
            step_kernel<<<32, 256, 0, stream>>>(nullptr, nullptr, nullptr, 0,
                                                nullptr, hc, nullptr, nullptr, 0,
                                                fcW, fcb, out + (size_t)tt * DXX, pred);
            step_kernel<<<256, 256, 0, stream>>>(dWhh, dWih, pred, DXX,
                                                 dec_b, hc, cF, hn, 256,
                                                 nullptr, nullptr, nullptr, nullptr);
            float* tmp = hc; hc = hn; hn = tmp;
        }
    }
    step_kernel<<<32, 256, 0, stream>>>(nullptr, nullptr, nullptr, 0,
                                        nullptr, hc, nullptr, nullptr, 0,
                                        fcW, fcb, out + (size_t)(TN - 1) * DXX, nullptr);
}

// Round 9
// 5177.366 us; speedup vs baseline: 1.2720x; 1.2720x over previous
//
#include <hip/hip_runtime.h>

// Seq2Seq LSTM (B=64, S=T=256, DIN=DOUT=128, H=1024).
// Round 9: round-8 write-once hseq chain (zero cache-maintenance) +
// round-7 low-poller tree barrier (t0-only, 16 leaves -> root -> 16 epoch
// replicas; NO acquire needed since no address is ever stale) +
// VGPR-pinned weights (asm "+v" makes fragments opaque so the compiler
// cannot rematerialize the 18 weight loads per step; r7/r8 VGPR=64 proved
// it was re-loading them from L2 every step).
//   - h stores: relaxed agent u32 atomics (MALL-direct, never dirty L2).
//   - h loads:  plain cached dwordx4 (cold miss -> MALL -> always fresh).
//   - weights/srcp: plain cached, L2-hot forever (never invalidated).
// hist merged into hseq (decoder h_t = hseq[257+t-1]); fc_batch reads it.
// c-state in registers. Split-bf16 (3 MFMA per fragment, fp32 accum).

#define BB   64
#define HH   1024
#define G4   4096
#define DXX  128
#define KC   128
#define SEQN 256
#define TN   256
#define OUT_BSTRIDE (TN * DXX)

#define HROW 2048                 // h row: [h_hi 1024][h_lo 1024]
#define SLOT (64 * HROW)          // one h buffer: 131072 halves = 256 KB

typedef __attribute__((ext_vector_type(8))) short short8;
typedef __attribute__((ext_vector_type(4))) float f32x4;

__device__ __forceinline__ float sigm(float x)  { return 1.f / (1.f + __expf(-x)); }
__device__ __forceinline__ float tanh_f(float x){ return 1.f - 2.f / (1.f + __expf(2.f * x)); }

__device__ __forceinline__ unsigned short bf16_rn(float x) {
    union { float f; unsigned u; } v; v.f = x;
    unsigned r = v.u + 0x7fffu + ((v.u >> 16) & 1u);
    return (unsigned short)(r >> 16);
}
__device__ __forceinline__ float bf16f(unsigned short h) {
    union { unsigned u; float f; } v; v.u = ((unsigned)h) << 16; return v.f;
}

// ================= persistent step =================
// KT=9 (+XPART: kw==3,kt>=5 read x from xs) or KT=8 (pure h).
template<int KT, bool XPART>
__device__ __forceinline__ void do_step(
    const short8 (&w)[9][2],
    const unsigned short* __restrict__ A,    // hseq[s]   (read, cached)
    unsigned short* __restrict__ An,         // hseq[s+1] (write, MALL)
    float* red, int mrow, int kl, int kw, int rbase,
    int t, int b, int nl, int nh, const float (&bb)[4], float& creg,
    const unsigned short* __restrict__ xs,   // [64][256] hi|lo (immutable) or null
    unsigned* __restrict__ bar, unsigned step)
{
    f32x4 acc = {0.f, 0.f, 0.f, 0.f};
    const unsigned short* Ar = A + mrow * HROW;
    #pragma unroll
    for (int kt = 0; kt < KT; ++kt) {
        const int kg = kw * (KT * 32) + kt * 32 + kl;
        short8 ah, al;
        if (XPART && kw == 3 && kt >= 5) {
            const int xo = mrow * 256 + (kg - 1024);
            ah = *(const short8*)(xs + xo);
            al = *(const short8*)(xs + xo + 128);
        } else {
            ah = *(const short8*)(Ar + kg);          // cached, cold-miss -> MALL
            al = *(const short8*)(Ar + 1024 + kg);
        }
        acc = __builtin_amdgcn_mfma_f32_16x16x32_bf16(ah, w[kt][0], acc, 0, 0, 0);
        acc = __builtin_amdgcn_mfma_f32_16x16x32_bf16(ah, w[kt][1], acc, 0, 0, 0);
        acc = __builtin_amdgcn_mfma_f32_16x16x32_bf16(al, w[kt][0], acc, 0, 0, 0);
    }
    #pragma unroll
    for (int r = 0; r < 4; ++r) red[rbase + r * 17] = acc[r];
    __syncthreads();

    if (t < 256) {
        float g4[4];
        #pragma unroll
        for (int gt = 0; gt < 4; ++gt) {
            const int cc = nl * 4 + gt;
            g4[gt] = red[b * 17 + cc] + red[(64 + b) * 17 + cc]
                   + red[(128 + b) * 17 + cc] + red[(192 + b) * 17 + cc] + bb[gt];
        }
        const float cv = sigm(g4[1]) * creg + sigm(g4[0]) * tanh_f(g4[2]);
        creg = cv;
        const float hv = sigm(g4[3]) * tanh_f(cv);
        const unsigned short hh = bf16_rn(hv);
        const unsigned short hl = bf16_rn(hv - bf16f(hh));
        // pair (nl even | nl odd) into one u32 MALL store each for hi and lo
        const unsigned phh = (unsigned)__shfl_xor((int)(unsigned)hh, 1);
        const unsigned phl = (unsigned)__shfl_xor((int)(unsigned)hl, 1);
        if ((nl & 1) == 0) {
            const unsigned wh = (unsigned)hh | (phh << 16);
            const unsigned wl = (unsigned)hl | (phl << 16);
            __hip_atomic_store((unsigned*)(An + b * HROW + nh), wh,
                               __ATOMIC_RELAXED, __HIP_MEMORY_SCOPE_AGENT);
            __hip_atomic_store((unsigned*)(An + b * HROW + 1024 + nh), wl,
                               __ATOMIC_RELAXED, __HIP_MEMORY_SCOPE_AGENT);
        }
    }
    // -------- device barrier: relaxed tree, t0-only poll, no cache ops --------
    __syncthreads();   // vmcnt drain: all MALL stores above are acked
    if (t == 0) {
        const int lf = blockIdx.x & 15;
        unsigned* leaf  = bar + lf * 32;          // 128 B apart
        unsigned* root  = bar + 16 * 32;
        unsigned* epoch = bar + (17 + lf) * 32;   // per-leaf epoch replica
        const unsigned a = __hip_atomic_fetch_add(leaf, 1u, __ATOMIC_RELAXED,
                                                  __HIP_MEMORY_SCOPE_AGENT);
        if (a == step * 16u - 1u) {                        // last of 16 at this leaf
            const unsigned r = __hip_atomic_fetch_add(root, 1u, __ATOMIC_RELAXED,
                                                      __HIP_MEMORY_SCOPE_AGENT);
            if (r == step * 16u - 1u) {                    // last leaf overall
                #pragma unroll
                for (int e = 0; e < 16; ++e)
                    __hip_atomic_store(bar + (17 + e) * 32, step,
                                       __ATOMIC_RELAXED, __HIP_MEMORY_SCOPE_AGENT);
            }
        }
        while (__hip_atomic_load(epoch, __ATOMIC_RELAXED,
                                 __HIP_MEMORY_SCOPE_AGENT) < step)
            __builtin_amdgcn_s_sleep(1);
    }
    __syncthreads();
}

__global__ __launch_bounds__(1024, 1)
void persist(const unsigned short* __restrict__ Wencf,
             const unsigned short* __restrict__ Wdec0f,
             const unsigned short* __restrict__ Wcombf,
             const unsigned short* __restrict__ srcp,
             const unsigned short* __restrict__ trgp,
             const float* __restrict__ benc,
             const float* __restrict__ bdec0,
             const float* __restrict__ bcomb,
             unsigned short* __restrict__ hseq,   // [512][64][2048]
             unsigned* __restrict__ bar)
{
    __shared__ float red[4 * 64 * 17];
    const int t  = threadIdx.x;
    const int bi = blockIdx.x;
    const int l  = t & 63;
    const int wv = t >> 6;
    const int mw = wv & 3;
    const int kw = wv >> 2;
    const int lm = l & 15;
    const int kl = (l >> 4) << 3;
    const int mrow = mw * 16 + lm;
    const int rbase = (kw * 64 + mw * 16 + (l >> 4) * 4) * 17 + lm;
    const int b  = t >> 2;
    const int nl = t & 3;
    const int nh = bi * 4 + nl;

    short8 w[9][2];
    float bb[4];
    float creg = 0.f;
    unsigned step = 0;

    // ---- encoder phase: steps 0..255, hseq[s] -> hseq[s+1] ----
    {
        const unsigned short* wp = Wencf + ((size_t)(bi * 4 + kw) * 9) * 1024 + l * 8;
        #pragma unroll
        for (int kt = 0; kt < 9; ++kt) {
            w[kt][0] = *(const short8*)(wp + kt * 1024);
            w[kt][1] = *(const short8*)(wp + kt * 1024 + 512);
            asm volatile("" : "+v"(w[kt][0]), "+v"(w[kt][1]));   // pin in VGPRs
        }
    }
    if (t < 256) {
        #pragma unroll
        for (int g = 0; g < 4; ++g) bb[g] = benc[bi * 16 + nl * 4 + g];
    }
    for (int s = 0; s < 256; ++s) {
        ++step;
        do_step<9, true>(w, hseq + (size_t)s * SLOT, hseq + (size_t)(s + 1) * SLOT,
                         red, mrow, kl, kw, rbase, t, b, nl, nh, bb, creg,
                         srcp + (size_t)s * 16384, bar, step);
    }
    // ---- decoder step 0 (input = trg[:,0,:]): step 256 -> hseq[257] = h_1 ----
    {
        const unsigned short* wp = Wdec0f + ((size_t)(bi * 4 + kw) * 9) * 1024 + l * 8;
        #pragma unroll
        for (int kt = 0; kt < 9; ++kt) {
            w[kt][0] = *(const short8*)(wp + kt * 1024);
            w[kt][1] = *(const short8*)(wp + kt * 1024 + 512);
            asm volatile("" : "+v"(w[kt][0]), "+v"(w[kt][1]));
        }
    }
    if (t < 256) {
        #pragma unroll
        for (int g = 0; g < 4; ++g) bb[g] = bdec0[bi * 16 + nl * 4 + g];
    }
    ++step;
    do_step<9, true>(w, hseq + (size_t)256 * SLOT, hseq + (size_t)257 * SLOT,
                     red, mrow, kl, kw, rbase, t, b, nl, nh, bb, creg,
                     trgp, bar, step);
    // ---- decoder comb phase: steps 257..510 -> hseq[258..511] = h_2..h_255 ----
    {
        const unsigned short* wp = Wcombf + ((size_t)(bi * 4 + kw) * 8) * 1024 + l * 8;
        #pragma unroll
        for (int kt = 0; kt < 8; ++kt) {
            w[kt][0] = *(const short8*)(wp + kt * 1024);
            w[kt][1] = *(const short8*)(wp + kt * 1024 + 512);
            asm volatile("" : "+v"(w[kt][0]), "+v"(w[kt][1]));
        }
    }
    if (t < 256) {
        #pragma unroll
        for (int g = 0; g < 4; ++g) bb[g] = bcomb[bi * 16 + nl * 4 + g];
    }
    for (int s = 257; s < 511; ++s) {
        ++step;
        do_step<8, false>(w, hseq + (size_t)s * SLOT, hseq + (size_t)(s + 1) * SLOT,
                          red, mrow, kl, kw, rbase, t, b, nl, nh, bb, creg,
                          nullptr, bar, step);
    }
}

// ================= batched FC over hseq[257..511] =================
// block bi (0..254): out[:, bi+1, :] = hseq[257+bi] @ fcW^T + fcb
__global__ __launch_bounds__(256)
void fc_batch(const unsigned short* __restrict__ fcf,   // [256 frags][1024]
              const unsigned short* __restrict__ hseq,
              const float* __restrict__ fcb,
              float* __restrict__ out)
{
    const int t = threadIdx.x, bi = blockIdx.x;
    const int l = t & 63, wv = t >> 6;
    const int lm = l & 15, kl = (l >> 4) << 3;
    const int mrow = wv * 16 + lm;
    const unsigned short* Ar = hseq + (size_t)(257 + bi) * SLOT + mrow * HROW;

    f32x4 acc[8];
    #pragma unroll
    for (int nt = 0; nt < 8; ++nt) acc[nt] = f32x4{0.f, 0.f, 0.f, 0.f};

    for (int kt = 0; kt < 32; ++kt) {
        const short8 ah = *(const short8*)(Ar + kt * 32 + kl);
        const short8 al = *(const short8*)(Ar + 1024 + kt * 32 + kl);
        #pragma unroll
        for (int nt = 0; nt < 8; ++nt) {
            const unsigned short* bp = fcf + (size_t)(nt * 32 + kt) * 1024 + l * 8;
            const short8 bh = *(const short8*)bp;
            const short8 bl = *(const short8*)(bp + 512);
            acc[nt] = __builtin_amdgcn_mfma_f32_16x16x32_bf16(ah, bh, acc[nt], 0, 0, 0);
            acc[nt] = __builtin_amdgcn_mfma_f32_16x16x32_bf16(ah, bl, acc[nt], 0, 0, 0);
            acc[nt] = __builtin_amdgcn_mfma_f32_16x16x32_bf16(al, bh, acc[nt], 0, 0, 0);
        }
    }
    #pragma unroll
    for (int nt = 0; nt < 8; ++nt) {
        const float bv = fcb[nt * 16 + lm];
        #pragma unroll
        for (int r = 0; r < 4; ++r) {
            const int bq = wv * 16 + (l >> 4) * 4 + r;
            out[(size_t)bq * OUT_BSTRIDE + (size_t)(bi + 1) * DXX + nt * 16 + lm] = acc[nt][r] + bv;
        }
    }
}

// ================= prep kernels =================
__global__ __launch_bounds__(256)
void prep_frag_12(const float* __restrict__ Whh, const float* __restrict__ Wih,
                  unsigned short* __restrict__ dst)   // KT=9, K=1152 [Whh|Wih]
{
    const int idx = blockIdx.x * 256 + threadIdx.x;   // 0..589823
    const int l = idx & 63;
    const int fid = idx >> 6;
    const int kt = fid % 9;
    const int rem = fid / 9;
    const int kw = rem & 3;
    const int biq = rem >> 2;
    const int col = biq * 16 + (l & 15);
    const int hid = col >> 2, g = col & 3;
    const int k0 = kw * 288 + kt * 32 + ((l >> 4) << 3);
    short8 vh, vl;
    #pragma unroll
    for (int e = 0; e < 8; ++e) {
        const int k = k0 + e;
        const float wv = (k < 1024) ? Whh[(size_t)(g * 1024 + hid) * 1024 + k]
                                    : Wih[(size_t)(g * 1024 + hid) * 128 + (k - 1024)];
        const unsigned short hi = bf16_rn(wv);
        vh[e] = (short)hi;
        vl[e] = (short)bf16_rn(wv - bf16f(hi));
    }
    *(short8*)(dst + (size_t)fid * 1024 + l * 8) = vh;
    *(short8*)(dst + (size_t)fid * 1024 + 512 + l * 8) = vl;
}

__global__ __launch_bounds__(256)
void prep_frag_comb(const float* __restrict__ Wc, unsigned short* __restrict__ dst)
{
    const int idx = blockIdx.x * 256 + threadIdx.x;   // 0..524287
    const int l = idx & 63;
    const int fid = idx >> 6;
    const int kt = fid & 7;
    const int rem = fid >> 3;
    const int kw = rem & 3;
    const int biq = rem >> 2;
    const int col = biq * 16 + (l & 15);
    const int hid = col >> 2, g = col & 3;
    const int k0 = kw * 256 + kt * 32 + ((l >> 4) << 3);
    short8 vh, vl;
    #pragma unroll
    for (int e = 0; e < 8; ++e) {
        const float wv = Wc[(size_t)(g * 1024 + hid) * 1024 + k0 + e];
        const unsigned short hi = bf16_rn(wv);
        vh[e] = (short)hi;
        vl[e] = (short)bf16_rn(wv - bf16f(hi));
    }
    *(short8*)(dst + (size_t)fid * 1024 + l * 8) = vh;
    *(short8*)(dst + (size_t)fid * 1024 + 512 + l * 8) = vl;
}

__global__ __launch_bounds__(256)
void prep_frag_fc(const float* __restrict__ fcW, unsigned short* __restrict__ dst)
{
    const int idx = blockIdx.x * 256 + threadIdx.x;   // 0..16383
    const int l = idx & 63;
    const int fid = idx >> 6;                          // nt*32 + kt
    const int nt = fid >> 5, kt = fid & 31;
    const int col = nt * 16 + (l & 15);
    const int k0 = kt * 32 + ((l >> 4) << 3);
    short8 vh, vl;
    #pragma unroll
    for (int e = 0; e < 8; ++e) {
        const float wv = fcW[(size_t)col * 1024 + k0 + e];
        const unsigned short hi = bf16_rn(wv);
        vh[e] = (short)hi;
        vl[e] = (short)bf16_rn(wv - bf16f(hi));
    }
    *(short8*)(dst + (size_t)fid * 1024 + l * 8) = vh;
    *(short8*)(dst + (size_t)fid * 1024 + 512 + l * 8) = vl;
}

__global__ __launch_bounds__(256)
void prep_bias_p(const float* __restrict__ ebi, const float* __restrict__ ebh,
                 const float* __restrict__ dbi, const float* __restrict__ dbh,
                 const float* __restrict__ dWih, const float* __restrict__ fcb,
                 float* __restrict__ benc, float* __restrict__ bdec0,
                 float* __restrict__ bcomb)
{
    const int idx = blockIdx.x * 256 + threadIdx.x;   // grid 16 -> 4096
    const int orig = ((idx & 3) << 10) | (idx >> 2);
    benc[idx] = ebi[orig] + ebh[orig];
    const float db = dbi[orig] + dbh[orig];
    bdec0[idx] = db;
    float a = db;
    const float* wr = dWih + (size_t)orig * DXX;
    for (int d = 0; d < DXX; ++d) a += wr[d] * fcb[d];
    bcomb[idx] = a;
}

__global__ __launch_bounds__(256)
void prep_src(const float* __restrict__ src, unsigned short* __restrict__ so, int n)
{
    const int idx = blockIdx.x * 256 + threadIdx.x;
    if (idx < n) {
        const int b = idx >> 15, s = (idx >> 7) & 255, d = idx & 127;
        const float v = src[idx];
        const unsigned short hi = bf16_rn(v);
        unsigned short* dst = so + ((size_t)s * 64 + b) * 256 + d;
        dst[0]   = hi;
        dst[128] = bf16_rn(v - bf16f(hi));
    }
}

__global__ __launch_bounds__(256)
void prep_trg0(const float* __restrict__ trg, unsigned short* __restrict__ tp)
{
    const int idx = blockIdx.x * 256 + threadIdx.x;   // grid 32 -> 8192
    const int bq = idx >> 7, d = idx & 127;
    const float v = trg[(size_t)bq * TN * DXX + d];
    const unsigned short hi = bf16_rn(v);
    tp[bq * 256 + d] = hi;
    tp[bq * 256 + 128 + d] = bf16_rn(v - bf16f(hi));
}

__global__ __launch_bounds__(256)
void init_persist(unsigned short* __restrict__ hseq, float* __restrict__ out,
                  unsigned* __restrict__ bar)
{
    const int idx = blockIdx.x * 256 + threadIdx.x;   // grid 296 -> 75776
    if (idx < SLOT / 2) {                              // zero hseq[0] as u32
        ((unsigned*)hseq)[idx] = 0u;
    } else if (idx < SLOT / 2 + BB * DXX) {
        const int r = idx - SLOT / 2;
        out[(size_t)(r >> 7) * OUT_BSTRIDE + (r & 127)] = 0.f;
    } else if (idx < SLOT / 2 + BB * DXX + 2048) {
        // barrier words: MALL-direct zeros (pollers read MALL)
        __hip_atomic_store(bar + (idx - (SLOT / 2 + BB * DXX)), 0u,
                           __ATOMIC_RELAXED, __HIP_MEMORY_SCOPE_AGENT);
    }
}

// ================= fp32 fallback (round-1 path) =================
__global__ __launch_bounds__(256)
void step_kernel(const float* __restrict__ W, const float* __restrict__ Wx,
                 const float* __restrict__ x, int xstride,
                 const float* __restrict__ bias,
                 const float* __restrict__ h_in, float* __restrict__ c,
                 float* __restrict__ h_out, int nGates,
                 const float* __restrict__ fcW, const float* __restrict__ fcb,
                 float* __restrict__ fc_out, float* __restrict__ predbuf)
{
    __shared__ float hT[KC][BB + 1];
    __shared__ float wl[16][KC];
    const int t   = threadIdx.x;
    const int b   = t & 63;
    const int q   = t >> 6;
    const int col = t & (KC - 1);
    const int r0  = t >> 7;
    const int bi  = blockIdx.x;

    if (bi < nGates) {
        const int n0 = bi * 4;
        const int n  = n0 + q;
        float a0 = bias[n], a1 = bias[HH + n], a2 = bias[2 * HH + n], a3 = bias[3 * HH + n];
        for (int k0 = 0; k0 < HH; k0 += KC) {
            #pragma unroll
            for (int rr = 0; rr < BB; rr += 2)
                hT[col][rr + r0] = h_in[(rr + r0) * HH + k0 + col];
            #pragma unroll
            for (int rr = 0; rr < 16; rr += 2) {
                const int r = rr + r0;
                const int j = (r & 3) * HH + n0 + (r >> 2);
                wl[r][col] = W[(size_t)j * HH + k0 + col];
            }
            __syncthreads();
            #pragma unroll 8
            for (int k = 0; k < KC; k += 4) {
                const float4 w0 = *reinterpret_cast<const float4*>(&wl[q * 4 + 0][k]);
                const float4 w1 = *reinterpret_cast<const float4*>(&wl[q * 4 + 1][k]);
                const float4 w2 = *reinterpret_cast<const float4*>(&wl[q * 4 + 2][k]);
                const float4 w3 = *reinterpret_cast<const float4*>(&wl[q * 4 + 3][k]);
                const float h0v = hT[k][b], h1v = hT[k + 1][b];
                const float h2v = hT[k + 2][b], h3v = hT[k + 3][b];
                a0 += h0v * w0.x + h1v * w0.y + h2v * w0.z + h3v * w0.w;
                a1 += h0v * w1.x + h1v * w1.y + h2v * w1.z + h3v * w1.w;
                a2 += h0v * w2.x + h1v * w2.y + h2v * w2.z + h3v * w2.w;
                a3 += h0v * w3.x + h1v * w3.y + h2v * w3.z + h3v * w3.w;
            }
            __syncthreads();
        }
        if (Wx != nullptr) {
            #pragma unroll
            for (int rr = 0; rr < BB; rr += 2)
                hT[col][rr + r0] = x[(size_t)(rr + r0) * xstride + col];
            #pragma unroll
            for (int rr = 0; rr < 16; rr += 2) {
                const int r = rr + r0;
                const int j = (r & 3) * HH + n0 + (r >> 2);
                wl[r][col] = Wx[(size_t)j * DXX + col];
            }
            __syncthreads();
            #pragma unroll 8
            for (int k = 0; k < DXX; k += 4) {
                const float4 w0 = *reinterpret_cast<const float4*>(&wl[q * 4 + 0][k]);
                const float4 w1 = *reinterpret_cast<const float4*>(&wl[q * 4 + 1][k]);
                const float4 w2 = *reinterpret_cast<const float4*>(&wl[q * 4 + 2][k]);
                const float4 w3 = *reinterpret_cast<const float4*>(&wl[q * 4 + 3][k]);
                const float h0v = hT[k][b], h1v = hT[k + 1][b];
                const float h2v = hT[k + 2][b], h3v = hT[k + 3][b];
                a0 += h0v * w0.x + h1v * w0.y + h2v * w0.z + h3v * w0.w;
                a1 += h0v * w1.x + h1v * w1.y + h2v * w1.z + h3v * w1.w;
                a2 += h0v * w2.x + h1v * w2.y + h2v * w2.z + h3v * w2.w;
                a3 += h0v * w3.x + h1v * w3.y + h2v * w3.z + h3v * w3.w;
            }
        }
        const int ci = b * HH + n;
        const float cv = sigm(a1) * c[ci] + sigm(a0) * tanh_f(a2);
        c[ci] = cv;
        h_out[ci] = sigm(a3) * tanh_f(cv);
    } else if (fcW != nullptr && bi < nGates + 32) {
        const int d0 = (bi - nGates) * 4;
        float a = 0.f;
        for (int k0 = 0; k0 < HH; k0 += KC) {
            #pragma unroll
            for (int rr = 0; rr < BB; rr += 2)
                hT[col][rr + r0] = h_in[(rr + r0) * HH + k0 + col];
            #pragma unroll
            for (int rr = 0; rr < 4; rr += 2)
                wl[rr + r0][col] = fcW[(size_t)(d0 + rr + r0) * HH + k0 + col];
            __syncthreads();
            #pragma unroll 8
            for (int k = 0; k < KC; k += 4) {
                const float4 w0 = *reinterpret_cast<const float4*>(&wl[q][k]);
                const float h0v = hT[k][b], h1v = hT[k + 1][b];
                const float h2v = hT[k + 2][b], h3v = hT[k + 3][b];
                a += h0v * w0.x + h1v * w0.y + h2v * w0.z + h3v * w0.w;
            }
            __syncthreads();
        }
        const int d = d0 + q;
        a += fcb[d];
        if (fc_out)  fc_out[(size_t)b * OUT_BSTRIDE + d] = a;
        if (predbuf) predbuf[b * DXX + d] = a;
    }
}

__global__ __launch_bounds__(256)
void bias_prep(const float* __restrict__ ebi, const float* __restrict__ ebh,
               const float* __restrict__ dbi, const float* __restrict__ dbh,
               const float* __restrict__ dWih, const float* __restrict__ fcbv,
               float* __restrict__ enc_b, float* __restrict__ dec_b, float* __restrict__ bcomb)
{
    __shared__ float fb[DXX];
    const int t = threadIdx.x;
    const int j = blockIdx.x * 256 + t;
    if (t < DXX) fb[t] = fcbv[t];
    __syncthreads();
    enc_b[j] = ebi[j] + ebh[j];
    const float db = dbi[j] + dbh[j];
    dec_b[j] = db;
    float acc = db;
    const float* wr = dWih + (size_t)j * DXX;
    for (int d = 0; d < DXX; d += 4) {
        const float4 w = *reinterpret_cast<const float4*>(&wr[d]);
        acc += w.x * fb[d] + w.y * fb[d + 1] + w.z * fb[d + 2] + w.w * fb[d + 3];
    }
    bcomb[j] = acc;
}

__global__ __launch_bounds__(256)
void wcomb_kernel(const float* __restrict__ dWhh, const float* __restrict__ dWih,
                  const float* __restrict__ fcW, float* __restrict__ Wcomb)
{
    const int bi = blockIdx.x;
    const int j0 = (bi >> 2) * 8;
    const int n  = (bi & 3) * 256 + threadIdx.x;
    __shared__ float wih[8][DXX];
    for (int i = threadIdx.x; i < 8 * DXX; i += 256)
        wih[i >> 7][i & 127] = dWih[(size_t)(j0 + (i >> 7)) * DXX + (i & 127)];
    __syncthreads();
    float acc[8];
    #pragma unroll
    for (int jj = 0; jj < 8; ++jj) acc[jj] = dWhh[(size_t)(j0 + jj) * HH + n];
    for (int d = 0; d < DXX; ++d) {
        const float fv = fcW[(size_t)d * HH + n];
        #pragma unroll
        for (int jj = 0; jj < 8; ++jj) acc[jj] += wih[jj][d] * fv;
    }
    #pragma unroll
    for (int jj = 0; jj < 8; ++jj) Wcomb[(size_t)(j0 + jj) * HH + n] = acc[jj];
}

__global__ __launch_bounds__(256)
void init_kernel(float* __restrict__ h0, float* __restrict__ c, float* __restrict__ out)
{
    const int idx = blockIdx.x * 256 + threadIdx.x;
    if (idx < BB * HH) h0[idx] = 0.f;
    else if (idx < 2 * BB * HH) c[idx - BB * HH] = 0.f;
    else {
        const int r = idx - 2 * BB * HH;
        if (r < BB * DXX) out[(size_t)(r >> 7) * OUT_BSTRIDE + (r & 127)] = 0.f;
    }
}

// ================= host =================
extern "C" void kernel_launch(void* const* d_in, const int* in_sizes, int n_in,
                              void* d_out, int out_size, void* d_ws, size_t ws_size,
                              hipStream_t stream) {
    const float* src   = (const float*)d_in[0];
    const float* trg   = (const float*)d_in[1];
    const float* eWih  = (const float*)d_in[2];
    const float* eWhh  = (const float*)d_in[3];
    const float* ebih  = (const float*)d_in[4];
    const float* ebhh  = (const float*)d_in[5];
    const float* dWih  = (const float*)d_in[6];
    const float* dWhh  = (const float*)d_in[7];
    const float* dbih  = (const float*)d_in[8];
    const float* dbhh  = (const float*)d_in[9];
    const float* fcW   = (const float*)d_in[10];
    const float* fcb   = (const float*)d_in[11];
    float* out = (float*)d_out;

    uintptr_t base = (uintptr_t)d_ws;
    size_t off = 0;
    auto alloc = [&](size_t bytes) -> void* {
        void* p = (void*)(base + off);
        off = (off + bytes + 255) & ~(size_t)255;
        return p;
    };
    unsigned* bar = (unsigned*)alloc(8192);
    unsigned short* srcp = (unsigned short*)alloc((size_t)SEQN * 64 * 256 * 2);
    unsigned short* trgp = (unsigned short*)alloc((size_t)64 * 256 * 2);
    float* benc  = (float*)alloc(G4 * 4);
    float* bdec0 = (float*)alloc(G4 * 4);
    float* bcomb = (float*)alloc(G4 * 4);
    unsigned short* fcf    = (unsigned short*)alloc((size_t)256 * 1024 * 2);
    unsigned short* Wencf  = (unsigned short*)alloc((size_t)9216 * 1024 * 2);
    unsigned short* Wdec0f = (unsigned short*)alloc((size_t)9216 * 1024 * 2);
    unsigned short* Wcombf = (unsigned short*)alloc((size_t)8192 * 1024 * 2);
    float* Wcomb32 = (float*)alloc((size_t)G4 * HH * 4);
    unsigned short* hseq   = (unsigned short*)alloc((size_t)512 * SLOT * 2);
    const bool fastok = (off <= ws_size);

    if (fastok) {
        init_persist<<<296, 256, 0, stream>>>(hseq, out, bar);
        prep_src<<<8192, 256, 0, stream>>>(src, srcp, BB * SEQN * DXX);
        prep_trg0<<<32, 256, 0, stream>>>(trg, trgp);
        prep_bias_p<<<16, 256, 0, stream>>>(ebih, ebhh, dbih, dbhh, dWih, fcb,
                                            benc, bdec0, bcomb);
        prep_frag_12<<<2304, 256, 0, stream>>>(eWhh, eWih, Wencf);
        prep_frag_12<<<2304, 256, 0, stream>>>(dWhh, dWih, Wdec0f);
        wcomb_kernel<<<2048, 256, 0, stream>>>(dWhh, dWih, fcW, Wcomb32);
        prep_frag_comb<<<2048, 256, 0, stream>>>(Wcomb32, Wcombf);
        prep_frag_fc<<<64, 256, 0, stream>>>(fcW, fcf);

        persist<<<256, 1024, 0, stream>>>(Wencf, Wdec0f, Wcombf, srcp, trgp,
                                          benc, bdec0, bcomb, hseq, bar);
        fc_batch<<<255, 256, 0, stream>>>(fcf, hseq, fcb, out);
        return;
    }

    // ---- fallback: fp32 per-step path ----
    float* ws  = (float*)d_ws;
    float* h0     = ws;
    float* h1     = ws + 65536;
    float* cF     = ws + 131072;
    float* pred   = ws + 196608;
    float* enc_b  = ws + 204800;
    float* dec_b  = ws + 208896;
    float* bcombF = ws + 212992;
    float* Wcomb  = ws + 217088;
    const bool use_comb = ws_size >= (size_t)(217088 + 4096 * 1024) * sizeof(float);

    init_kernel<<<544, 256, 0, stream>>>(h0, cF, out);
    bias_prep<<<16, 256, 0, stream>>>(ebih, ebhh, dbih, dbhh, dWih, fcb, enc_b, dec_b, bcombF);
    if (use_comb)
        wcomb_kernel<<<2048, 256, 0, stream>>>(dWhh, dWih, fcW, Wcomb);

    float* hc = h0;
    float* hn = h1;
    for (int s = 0; s < SEQN; ++s) {
        step_kernel<<<256, 256, 0, stream>>>(eWhh, eWih, src + s * DXX, SEQN * DXX,
                                             enc_b, hc, cF, hn, 256,
                                             nullptr, nullptr, nullptr, nullptr);
        float* tmp = hc; hc = hn; hn = tmp;
    }
    step_kernel<<<256, 256, 0, stream>>>(dWhh, dWih, trg, TN * DXX,
                                         dec_b, hc, cF, hn, 256,
                                         nullptr, nullptr, nullptr, nullptr);
    { float* tmp = hc; hc = hn; hn = tmp; }
    if (use_comb) {
        for (int tt = 1; tt <= TN - 2; ++tt) {
            step_kernel<<<288, 256, 0, stream>>>(Wcomb, nullptr, nullptr, 0,
                                                 bcombF, hc, cF, hn, 256,
                                                 fcW, fcb, out + (size_t)tt * DXX, nullptr);
            float* tmp = hc; hc = hn; hn = tmp;
        }
    } else {
        for (int tt = 1; tt <= TN - 2; ++tt) {
            step_kernel<<<32, 256, 0, stream>>>(nullptr, nullptr, nullptr, 0,
                                                nullptr, hc, nullptr, nullptr, 0,
                                                fcW, fcb, out + (size_t)tt * DXX, pred);
            step_kernel<<<256, 256, 0, stream>>>(dWhh, dWih, pred, DXX,
                                                 dec_b, hc, cF, hn, 256,
                                                 nullptr, nullptr, nullptr, nullptr);
            float* tmp = hc; hc = hn; hn = tmp;
        }
    }
    step_kernel<<<32, 256, 0, stream>>>(nullptr, nullptr, nullptr, 0,
                                        nullptr, hc, nullptr, nullptr, 0,
                                        fcW, fcb, out + (size_t)(TN - 1) * DXX, nullptr);
}

// Round 10
// 5137.831 us; speedup vs baseline: 1.2818x; 1.0077x over previous
//
#include <hip/hip_runtime.h>

// Seq2Seq LSTM (B=64, S=T=256, DIN=DOUT=128, H=1024).
// Round 10: round-9 write-once hseq chain + VGPR-pinned weights, with the
// tree-RMW barrier replaced by a CONTENTION-FREE store-slot barrier:
//   - arrival: plain relaxed agent store to slot[bi] (256 distinct words,
//     no RMW, no serialization).
//   - detection: block 0 wave 0 polls all 256 slots (4 per lane, __all
//     ballot), then lanes 0..15 store 16 epoch replicas IN PARALLEL.
//   - wait: t0-only poll of this block's epoch replica (16 pollers/line).
// Round-9's fetch_add tree serialized ~16 RMWs per leaf line per step
// (~2-4 us of queued RMWs after last arrival) - all gone now.
//   - h stores: relaxed agent u32 atomics (MALL-direct, never dirty L2).
//   - h loads:  plain cached dwordx4 (cold miss -> MALL -> always fresh).
//   - weights/srcp: plain cached, L2-hot forever (never invalidated).
// hist merged into hseq (decoder h_t = hseq[257+t-1]); fc_batch reads it.
// c-state in registers. Split-bf16 (3 MFMA per fragment, fp32 accum).

#define BB   64
#define HH   1024
#define G4   4096
#define DXX  128
#define KC   128
#define SEQN 256
#define TN   256
#define OUT_BSTRIDE (TN * DXX)

#define HROW 2048                 // h row: [h_hi 1024][h_lo 1024]
#define SLOT (64 * HROW)          // one h buffer: 131072 halves = 256 KB

typedef __attribute__((ext_vector_type(8))) short short8;
typedef __attribute__((ext_vector_type(4))) float f32x4;

__device__ __forceinline__ float sigm(float x)  { return 1.f / (1.f + __expf(-x)); }
__device__ __forceinline__ float tanh_f(float x){ return 1.f - 2.f / (1.f + __expf(2.f * x)); }

__device__ __forceinline__ unsigned short bf16_rn(float x) {
    union { float f; unsigned u; } v; v.f = x;
    unsigned r = v.u + 0x7fffu + ((v.u >> 16) & 1u);
    return (unsigned short)(r >> 16);
}
__device__ __forceinline__ float bf16f(unsigned short h) {
    union { unsigned u; float f; } v; v.u = ((unsigned)h) << 16; return v.f;
}

// ================= persistent step =================
// KT=9 (+XPART: kw==3,kt>=5 read x from xs) or KT=8 (pure h).
// bar layout: slots[0..255] (u32), epoch replica lf at bar + 256 + lf*32.
template<int KT, bool XPART>
__device__ __forceinline__ void do_step(
    const short8 (&w)[9][2],
    const unsigned short* __restrict__ A,    // hseq[s]   (read, cached)
    unsigned short* __restrict__ An,         // hseq[s+1] (write, MALL)
    float* red, int mrow, int kl, int kw, int rbase,
    int t, int b, int nl, int nh, const float (&bb)[4], float& creg,
    const unsigned short* __restrict__ xs,   // [64][256] hi|lo (immutable) or null
    unsigned* __restrict__ bar, unsigned step)
{
    f32x4 acc = {0.f, 0.f, 0.f, 0.f};
    const unsigned short* Ar = A + mrow * HROW;
    #pragma unroll
    for (int kt = 0; kt < KT; ++kt) {
        const int kg = kw * (KT * 32) + kt * 32 + kl;
        short8 ah, al;
        if (XPART && kw == 3 && kt >= 5) {
            const int xo = mrow * 256 + (kg - 1024);
            ah = *(const short8*)(xs + xo);
            al = *(const short8*)(xs + xo + 128);
        } else {
            ah = *(const short8*)(Ar + kg);          // cached, cold-miss -> MALL
            al = *(const short8*)(Ar + 1024 + kg);
        }
        acc = __builtin_amdgcn_mfma_f32_16x16x32_bf16(ah, w[kt][0], acc, 0, 0, 0);
        acc = __builtin_amdgcn_mfma_f32_16x16x32_bf16(ah, w[kt][1], acc, 0, 0, 0);
        acc = __builtin_amdgcn_mfma_f32_16x16x32_bf16(al, w[kt][0], acc, 0, 0, 0);
    }
    #pragma unroll
    for (int r = 0; r < 4; ++r) red[rbase + r * 17] = acc[r];
    __syncthreads();

    if (t < 256) {
        float g4[4];
        #pragma unroll
        for (int gt = 0; gt < 4; ++gt) {
            const int cc = nl * 4 + gt;
            g4[gt] = red[b * 17 + cc] + red[(64 + b) * 17 + cc]
                   + red[(128 + b) * 17 + cc] + red[(192 + b) * 17 + cc] + bb[gt];
        }
        const float cv = sigm(g4[1]) * creg + sigm(g4[0]) * tanh_f(g4[2]);
        creg = cv;
        const float hv = sigm(g4[3]) * tanh_f(cv);
        const unsigned short hh = bf16_rn(hv);
        const unsigned short hl = bf16_rn(hv - bf16f(hh));
        // pair (nl even | nl odd) into one u32 MALL store each for hi and lo
        const unsigned phh = (unsigned)__shfl_xor((int)(unsigned)hh, 1);
        const unsigned phl = (unsigned)__shfl_xor((int)(unsigned)hl, 1);
        if ((nl & 1) == 0) {
            const unsigned wh = (unsigned)hh | (phh << 16);
            const unsigned wl = (unsigned)hl | (phl << 16);
            __hip_atomic_store((unsigned*)(An + b * HROW + nh), wh,
                               __ATOMIC_RELAXED, __HIP_MEMORY_SCOPE_AGENT);
            __hip_atomic_store((unsigned*)(An + b * HROW + 1024 + nh), wl,
                               __ATOMIC_RELAXED, __HIP_MEMORY_SCOPE_AGENT);
        }
    }
    // -------- device barrier: store-slots + detector wave, no RMW --------
    __syncthreads();   // vmcnt drain: all MALL stores above are acked
    if (t == 0)
        __hip_atomic_store(bar + blockIdx.x, step,
                           __ATOMIC_RELAXED, __HIP_MEMORY_SCOPE_AGENT);
    if (blockIdx.x == 0) {
        if (t < 64) {
            const unsigned* sp = bar + t * 4;       // each lane watches 4 slots
            for (;;) {
                const unsigned m0 = __hip_atomic_load(sp + 0, __ATOMIC_RELAXED, __HIP_MEMORY_SCOPE_AGENT);
                const unsigned m1 = __hip_atomic_load(sp + 1, __ATOMIC_RELAXED, __HIP_MEMORY_SCOPE_AGENT);
                const unsigned m2 = __hip_atomic_load(sp + 2, __ATOMIC_RELAXED, __HIP_MEMORY_SCOPE_AGENT);
                const unsigned m3 = __hip_atomic_load(sp + 3, __ATOMIC_RELAXED, __HIP_MEMORY_SCOPE_AGENT);
                const bool ok = (m0 >= step) & (m1 >= step) & (m2 >= step) & (m3 >= step);
                if (__all((int)ok)) break;
                __builtin_amdgcn_s_sleep(1);
            }
            if (t < 16)                              // 16 epoch replicas in parallel
                __hip_atomic_store(bar + 256 + t * 32, step,
                                   __ATOMIC_RELAXED, __HIP_MEMORY_SCOPE_AGENT);
        }
    } else if (t == 0) {
        const unsigned* ep = bar + 256 + (blockIdx.x & 15) * 32;
        while (__hip_atomic_load(ep, __ATOMIC_RELAXED,
                                 __HIP_MEMORY_SCOPE_AGENT) < step)
            __builtin_amdgcn_s_sleep(1);
    }
    __syncthreads();
}

__global__ __launch_bounds__(1024, 1)
void persist(const unsigned short* __restrict__ Wencf,
             const unsigned short* __restrict__ Wdec0f,
             const unsigned short* __restrict__ Wcombf,
             const unsigned short* __restrict__ srcp,
             const unsigned short* __restrict__ trgp,
             const float* __restrict__ benc,
             const float* __restrict__ bdec0,
             const float* __restrict__ bcomb,
             unsigned short* __restrict__ hseq,   // [512][64][2048]
             unsigned* __restrict__ bar)
{
    __shared__ float red[4 * 64 * 17];
    const int t  = threadIdx.x;
    const int bi = blockIdx.x;
    const int l  = t & 63;
    const int wv = t >> 6;
    const int mw = wv & 3;
    const int kw = wv >> 2;
    const int lm = l & 15;
    const int kl = (l >> 4) << 3;
    const int mrow = mw * 16 + lm;
    const int rbase = (kw * 64 + mw * 16 + (l >> 4) * 4) * 17 + lm;
    const int b  = t >> 2;
    const int nl = t & 3;
    const int nh = bi * 4 + nl;

    short8 w[9][2];
    float bb[4];
    float creg = 0.f;
    unsigned step = 0;

    // ---- encoder phase: steps 0..255, hseq[s] -> hseq[s+1] ----
    {
        const unsigned short* wp = Wencf + ((size_t)(bi * 4 + kw) * 9) * 1024 + l * 8;
        #pragma unroll
        for (int kt = 0; kt < 9; ++kt) {
            w[kt][0] = *(const short8*)(wp + kt * 1024);
            w[kt][1] = *(const short8*)(wp + kt * 1024 + 512);
            asm volatile("" : "+v"(w[kt][0]), "+v"(w[kt][1]));   // pin in VGPRs
        }
    }
    if (t < 256) {
        #pragma unroll
        for (int g = 0; g < 4; ++g) bb[g] = benc[bi * 16 + nl * 4 + g];
    }
    for (int s = 0; s < 256; ++s) {
        ++step;
        do_step<9, true>(w, hseq + (size_t)s * SLOT, hseq + (size_t)(s + 1) * SLOT,
                         red, mrow, kl, kw, rbase, t, b, nl, nh, bb, creg,
                         srcp + (size_t)s * 16384, bar, step);
    }
    // ---- decoder step 0 (input = trg[:,0,:]): step 256 -> hseq[257] = h_1 ----
    {
        const unsigned short* wp = Wdec0f + ((size_t)(bi * 4 + kw) * 9) * 1024 + l * 8;
        #pragma unroll
        for (int kt = 0; kt < 9; ++kt) {
            w[kt][0] = *(const short8*)(wp + kt * 1024);
            w[kt][1] = *(const short8*)(wp + kt * 1024 + 512);
            asm volatile("" : "+v"(w[kt][0]), "+v"(w[kt][1]));
        }
    }
    if (t < 256) {
        #pragma unroll
        for (int g = 0; g < 4; ++g) bb[g] = bdec0[bi * 16 + nl * 4 + g];
    }
    ++step;
    do_step<9, true>(w, hseq + (size_t)256 * SLOT, hseq + (size_t)257 * SLOT,
                     red, mrow, kl, kw, rbase, t, b, nl, nh, bb, creg,
                     trgp, bar, step);
    // ---- decoder comb phase: steps 257..510 -> hseq[258..511] = h_2..h_255 ----
    {
        const unsigned short* wp = Wcombf + ((size_t)(bi * 4 + kw) * 8) * 1024 + l * 8;
        #pragma unroll
        for (int kt = 0; kt < 8; ++kt) {
            w[kt][0] = *(const short8*)(wp + kt * 1024);
            w[kt][1] = *(const short8*)(wp + kt * 1024 + 512);
            asm volatile("" : "+v"(w[kt][0]), "+v"(w[kt][1]));
        }
    }
    if (t < 256) {
        #pragma unroll
        for (int g = 0; g < 4; ++g) bb[g] = bcomb[bi * 16 + nl * 4 + g];
    }
    for (int s = 257; s < 511; ++s) {
        ++step;
        do_step<8, false>(w, hseq + (size_t)s * SLOT, hseq + (size_t)(s + 1) * SLOT,
                          red, mrow, kl, kw, rbase, t, b, nl, nh, bb, creg,
                          nullptr, bar, step);
    }
}

// ================= batched FC over hseq[257..511] =================
// block bi (0..254): out[:, bi+1, :] = hseq[257+bi] @ fcW^T + fcb
__global__ __launch_bounds__(256)
void fc_batch(const unsigned short* __restrict__ fcf,   // [256 frags][1024]
              const unsigned short* __restrict__ hseq,
              const float* __restrict__ fcb,
              float* __restrict__ out)
{
    const int t = threadIdx.x, bi = blockIdx.x;
    const int l = t & 63, wv = t >> 6;
    const int lm = l & 15, kl = (l >> 4) << 3;
    const int mrow = wv * 16 + lm;
    const unsigned short* Ar = hseq + (size_t)(257 + bi) * SLOT + mrow * HROW;

    f32x4 acc[8];
    #pragma unroll
    for (int nt = 0; nt < 8; ++nt) acc[nt] = f32x4{0.f, 0.f, 0.f, 0.f};

    for (int kt = 0; kt < 32; ++kt) {
        const short8 ah = *(const short8*)(Ar + kt * 32 + kl);
        const short8 al = *(const short8*)(Ar + 1024 + kt * 32 + kl);
        #pragma unroll
        for (int nt = 0; nt < 8; ++nt) {
            const unsigned short* bp = fcf + (size_t)(nt * 32 + kt) * 1024 + l * 8;
            const short8 bh = *(const short8*)bp;
            const short8 bl = *(const short8*)(bp + 512);
            acc[nt] = __builtin_amdgcn_mfma_f32_16x16x32_bf16(ah, bh, acc[nt], 0, 0, 0);
            acc[nt] = __builtin_amdgcn_mfma_f32_16x16x32_bf16(ah, bl, acc[nt], 0, 0, 0);
            acc[nt] = __builtin_amdgcn_mfma_f32_16x16x32_bf16(al, bh, acc[nt], 0, 0, 0);
        }
    }
    #pragma unroll
    for (int nt = 0; nt < 8; ++nt) {
        const float bv = fcb[nt * 16 + lm];
        #pragma unroll
        for (int r = 0; r < 4; ++r) {
            const int bq = wv * 16 + (l >> 4) * 4 + r;
            out[(size_t)bq * OUT_BSTRIDE + (size_t)(bi + 1) * DXX + nt * 16 + lm] = acc[nt][r] + bv;
        }
    }
}

// ================= prep kernels =================
__global__ __launch_bounds__(256)
void prep_frag_12(const float* __restrict__ Whh, const float* __restrict__ Wih,
                  unsigned short* __restrict__ dst)   // KT=9, K=1152 [Whh|Wih]
{
    const int idx = blockIdx.x * 256 + threadIdx.x;   // 0..589823
    const int l = idx & 63;
    const int fid = idx >> 6;
    const int kt = fid % 9;
    const int rem = fid / 9;
    const int kw = rem & 3;
    const int biq = rem >> 2;
    const int col = biq * 16 + (l & 15);
    const int hid = col >> 2, g = col & 3;
    const int k0 = kw * 288 + kt * 32 + ((l >> 4) << 3);
    short8 vh, vl;
    #pragma unroll
    for (int e = 0; e < 8; ++e) {
        const int k = k0 + e;
        const float wv = (k < 1024) ? Whh[(size_t)(g * 1024 + hid) * 1024 + k]
                                    : Wih[(size_t)(g * 1024 + hid) * 128 + (k - 1024)];
        const unsigned short hi = bf16_rn(wv);
        vh[e] = (short)hi;
        vl[e] = (short)bf16_rn(wv - bf16f(hi));
    }
    *(short8*)(dst + (size_t)fid * 1024 + l * 8) = vh;
    *(short8*)(dst + (size_t)fid * 1024 + 512 + l * 8) = vl;
}

__global__ __launch_bounds__(256)
void prep_frag_comb(const float* __restrict__ Wc, unsigned short* __restrict__ dst)
{
    const int idx = blockIdx.x * 256 + threadIdx.x;   // 0..524287
    const int l = idx & 63;
    const int fid = idx >> 6;
    const int kt = fid & 7;
    const int rem = fid >> 3;
    const int kw = rem & 3;
    const int biq = rem >> 2;
    const int col = biq * 16 + (l & 15);
    const int hid = col >> 2, g = col & 3;
    const int k0 = kw * 256 + kt * 32 + ((l >> 4) << 3);
    short8 vh, vl;
    #pragma unroll
    for (int e = 0; e < 8; ++e) {
        const float wv = Wc[(size_t)(g * 1024 + hid) * 1024 + k0 + e];
        const unsigned short hi = bf16_rn(wv);
        vh[e] = (short)hi;
        vl[e] = (short)bf16_rn(wv - bf16f(hi));
    }
    *(short8*)(dst + (size_t)fid * 1024 + l * 8) = vh;
    *(short8*)(dst + (size_t)fid * 1024 + 512 + l * 8) = vl;
}

__global__ __launch_bounds__(256)
void prep_frag_fc(const float* __restrict__ fcW, unsigned short* __restrict__ dst)
{
    const int idx = blockIdx.x * 256 + threadIdx.x;   // 0..16383
    const int l = idx & 63;
    const int fid = idx >> 6;                          // nt*32 + kt
    const int nt = fid >> 5, kt = fid & 31;
    const int col = nt * 16 + (l & 15);
    const int k0 = kt * 32 + ((l >> 4) << 3);
    short8 vh, vl;
    #pragma unroll
    for (int e = 0; e < 8; ++e) {
        const float wv = fcW[(size_t)col * 1024 + k0 + e];
        const unsigned short hi = bf16_rn(wv);
        vh[e] = (short)hi;
        vl[e] = (short)bf16_rn(wv - bf16f(hi));
    }
    *(short8*)(dst + (size_t)fid * 1024 + l * 8) = vh;
    *(short8*)(dst + (size_t)fid * 1024 + 512 + l * 8) = vl;
}

__global__ __launch_bounds__(256)
void prep_bias_p(const float* __restrict__ ebi, const float* __restrict__ ebh,
                 const float* __restrict__ dbi, const float* __restrict__ dbh,
                 const float* __restrict__ dWih, const float* __restrict__ fcb,
                 float* __restrict__ benc, float* __restrict__ bdec0,
                 float* __restrict__ bcomb)
{
    const int idx = blockIdx.x * 256 + threadIdx.x;   // grid 16 -> 4096
    const int orig = ((idx & 3) << 10) | (idx >> 2);
    benc[idx] = ebi[orig] + ebh[orig];
    const float db = dbi[orig] + dbh[orig];
    bdec0[idx] = db;
    float a = db;
    const float* wr = dWih + (size_t)orig * DXX;
    for (int d = 0; d < DXX; ++d) a += wr[d] * fcb[d];
    bcomb[idx] = a;
}

__global__ __launch_bounds__(256)
void prep_src(const float* __restrict__ src, unsigned short* __restrict__ so, int n)
{
    const int idx = blockIdx.x * 256 + threadIdx.x;
    if (idx < n) {
        const int b = idx >> 15, s = (idx >> 7) & 255, d = idx & 127;
        const float v = src[idx];
        const unsigned short hi = bf16_rn(v);
        unsigned short* dst = so + ((size_t)s * 64 + b) * 256 + d;
        dst[0]   = hi;
        dst[128] = bf16_rn(v - bf16f(hi));
    }
}

__global__ __launch_bounds__(256)
void prep_trg0(const float* __restrict__ trg, unsigned short* __restrict__ tp)
{
    const int idx = blockIdx.x * 256 + threadIdx.x;   // grid 32 -> 8192
    const int bq = idx >> 7, d = idx & 127;
    const float v = trg[(size_t)bq * TN * DXX + d];
    const unsigned short hi = bf16_rn(v);
    tp[bq * 256 + d] = hi;
    tp[bq * 256 + 128 + d] = bf16_rn(v - bf16f(hi));
}

__global__ __launch_bounds__(256)
void init_persist(unsigned short* __restrict__ hseq, float* __restrict__ out,
                  unsigned* __restrict__ bar)
{
    const int idx = blockIdx.x * 256 + threadIdx.x;   // grid 296 -> 75776
    if (idx < SLOT / 2) {                              // zero hseq[0] as u32
        ((unsigned*)hseq)[idx] = 0u;
    } else if (idx < SLOT / 2 + BB * DXX) {
        const int r = idx - SLOT / 2;
        out[(size_t)(r >> 7) * OUT_BSTRIDE + (r & 127)] = 0.f;
    } else if (idx < SLOT / 2 + BB * DXX + 2048) {
        // barrier words (slots + epoch replicas): MALL-direct zeros
        __hip_atomic_store(bar + (idx - (SLOT / 2 + BB * DXX)), 0u,
                           __ATOMIC_RELAXED, __HIP_MEMORY_SCOPE_AGENT);
    }
}

// ================= fp32 fallback (round-1 path) =================
__global__ __launch_bounds__(256)
void step_kernel(const float* __restrict__ W, const float* __restrict__ Wx,
                 const float* __restrict__ x, int xstride,
                 const float* __restrict__ bias,
                 const float* __restrict__ h_in, float* __restrict__ c,
                 float* __restrict__ h_out, int nGates,
                 const float* __restrict__ fcW, const float* __restrict__ fcb,
                 float* __restrict__ fc_out, float* __restrict__ predbuf)
{
    __shared__ float hT[KC][BB + 1];
    __shared__ float wl[16][KC];
    const int t   = threadIdx.x;
    const int b   = t & 63;
    const int q   = t >> 6;
    const int col = t & (KC - 1);
    const int r0  = t >> 7;
    const int bi  = blockIdx.x;

    if (bi < nGates) {
        const int n0 = bi * 4;
        const int n  = n0 + q;
        float a0 = bias[n], a1 = bias[HH + n], a2 = bias[2 * HH + n], a3 = bias[3 * HH + n];
        for (int k0 = 0; k0 < HH; k0 += KC) {
            #pragma unroll
            for (int rr = 0; rr < BB; rr += 2)
                hT[col][rr + r0] = h_in[(rr + r0) * HH + k0 + col];
            #pragma unroll
            for (int rr = 0; rr < 16; rr += 2) {
                const int r = rr + r0;
                const int j = (r & 3) * HH + n0 + (r >> 2);
                wl[r][col] = W[(size_t)j * HH + k0 + col];
            }
            __syncthreads();
            #pragma unroll 8
            for (int k = 0; k < KC; k += 4) {
                const float4 w0 = *reinterpret_cast<const float4*>(&wl[q * 4 + 0][k]);
                const float4 w1 = *reinterpret_cast<const float4*>(&wl[q * 4 + 1][k]);
                const float4 w2 = *reinterpret_cast<const float4*>(&wl[q * 4 + 2][k]);
                const float4 w3 = *reinterpret_cast<const float4*>(&wl[q * 4 + 3][k]);
                const float h0v = hT[k][b], h1v = hT[k + 1][b];
                const float h2v = hT[k + 2][b], h3v = hT[k + 3][b];
                a0 += h0v * w0.x + h1v * w0.y + h2v * w0.z + h3v * w0.w;
                a1 += h0v * w1.x + h1v * w1.y + h2v * w1.z + h3v * w1.w;
                a2 += h0v * w2.x + h1v * w2.y + h2v * w2.z + h3v * w2.w;
                a3 += h0v * w3.x + h1v * w3.y + h2v * w3.z + h3v * w3.w;
            }
            __syncthreads();
        }
        if (Wx != nullptr) {
            #pragma unroll
            for (int rr = 0; rr < BB; rr += 2)
                hT[col][rr + r0] = x[(size_t)(rr + r0) * xstride + col];
            #pragma unroll
            for (int rr = 0; rr < 16; rr += 2) {
                const int r = rr + r0;
                const int j = (r & 3) * HH + n0 + (r >> 2);
                wl[r][col] = Wx[(size_t)j * DXX + col];
            }
            __syncthreads();
            #pragma unroll 8
            for (int k = 0; k < DXX; k += 4) {
                const float4 w0 = *reinterpret_cast<const float4*>(&wl[q * 4 + 0][k]);
                const float4 w1 = *reinterpret_cast<const float4*>(&wl[q * 4 + 1][k]);
                const float4 w2 = *reinterpret_cast<const float4*>(&wl[q * 4 + 2][k]);
                const float4 w3 = *reinterpret_cast<const float4*>(&wl[q * 4 + 3][k]);
                const float h0v = hT[k][b], h1v = hT[k + 1][b];
                const float h2v = hT[k + 2][b], h3v = hT[k + 3][b];
                a0 += h0v * w0.x + h1v * w0.y + h2v * w0.z + h3v * w0.w;
                a1 += h0v * w1.x + h1v * w1.y + h2v * w1.z + h3v * w1.w;
                a2 += h0v * w2.x + h1v * w2.y + h2v * w2.z + h3v * w2.w;
                a3 += h0v * w3.x + h1v * w3.y + h2v * w3.z + h3v * w3.w;
            }
        }
        const int ci = b * HH + n;
        const float cv = sigm(a1) * c[ci] + sigm(a0) * tanh_f(a2);
        c[ci] = cv;
        h_out[ci] = sigm(a3) * tanh_f(cv);
    } else if (fcW != nullptr && bi < nGates + 32) {
        const int d0 = (bi - nGates) * 4;
        float a = 0.f;
        for (int k0 = 0; k0 < HH; k0 += KC) {
            #pragma unroll
            for (int rr = 0; rr < BB; rr += 2)
                hT[col][rr + r0] = h_in[(rr + r0) * HH + k0 + col];
            #pragma unroll
            for (int rr = 0; rr < 4; rr += 2)
                wl[rr + r0][col] = fcW[(size_t)(d0 + rr + r0) * HH + k0 + col];
            __syncthreads();
            #pragma unroll 8
            for (int k = 0; k < KC; k += 4) {
                const float4 w0 = *reinterpret_cast<const float4*>(&wl[q][k]);
                const float h0v = hT[k][b], h1v = hT[k + 1][b];
                const float h2v = hT[k + 2][b], h3v = hT[k + 3][b];
                a += h0v * w0.x + h1v * w0.y + h2v * w0.z + h3v * w0.w;
            }
            __syncthreads();
        }
        const int d = d0 + q;
        a += fcb[d];
        if (fc_out)  fc_out[(size_t)b * OUT_BSTRIDE + d] = a;
        if (predbuf) predbuf[b * DXX + d] = a;
    }
}

__global__ __launch_bounds__(256)
void bias_prep(const float* __restrict__ ebi, const float* __restrict__ ebh,
               const float* __restrict__ dbi, const float* __restrict__ dbh,
               const float* __restrict__ dWih, const float* __restrict__ fcbv,
               float* __restrict__ enc_b, float* __restrict__ dec_b, float* __restrict__ bcomb)
{
    __shared__ float fb[DXX];
    const int t = threadIdx.x;
    const int j = blockIdx.x * 256 + t;
    if (t < DXX) fb[t] = fcbv[t];
    __syncthreads();
    enc_b[j] = ebi[j] + ebh[j];
    const float db = dbi[j] + dbh[j];
    dec_b[j] = db;
    float acc = db;
    const float* wr = dWih + (size_t)j * DXX;
    for (int d = 0; d < DXX; d += 4) {
        const float4 w = *reinterpret_cast<const float4*>(&wr[d]);
        acc += w.x * fb[d] + w.y * fb[d + 1] + w.z * fb[d + 2] + w.w * fb[d + 3];
    }
    bcomb[j] = acc;
}

__global__ __launch_bounds__(256)
void wcomb_kernel(const float* __restrict__ dWhh, const float* __restrict__ dWih,
                  const float* __restrict__ fcW, float* __restrict__ Wcomb)
{
    const int bi = blockIdx.x;
    const int j0 = (bi >> 2) * 8;
    const int n  = (bi & 3) * 256 + threadIdx.x;
    __shared__ float wih[8][DXX];
    for (int i = threadIdx.x; i < 8 * DXX; i += 256)
        wih[i >> 7][i & 127] = dWih[(size_t)(j0 + (i >> 7)) * DXX + (i & 127)];
    __syncthreads();
    float acc[8];
    #pragma unroll
    for (int jj = 0; jj < 8; ++jj) acc[jj] = dWhh[(size_t)(j0 + jj) * HH + n];
    for (int d = 0; d < DXX; ++d) {
        const float fv = fcW[(size_t)d * HH + n];
        #pragma unroll
        for (int jj = 0; jj < 8; ++jj) acc[jj] += wih[jj][d] * fv;
    }
    #pragma unroll
    for (int jj = 0; jj < 8; ++jj) Wcomb[(size_t)(j0 + jj) * HH + n] = acc[jj];
}

__global__ __launch_bounds__(256)
void init_kernel(float* __restrict__ h0, float* __restrict__ c, float* __restrict__ out)
{
    const int idx = blockIdx.x * 256 + threadIdx.x;
    if (idx < BB * HH) h0[idx] = 0.f;
    else if (idx < 2 * BB * HH) c[idx - BB * HH] = 0.f;
    else {
        const int r = idx - 2 * BB * HH;
        if (r < BB * DXX) out[(size_t)(r >> 7) * OUT_BSTRIDE + (r & 127)] = 0.f;
    }
}

// ================= host =================
extern "C" void kernel_launch(void* const* d_in, const int* in_sizes, int n_in,
                              void* d_out, int out_size, void* d_ws, size_t ws_size,
                              hipStream_t stream) {
    const float* src   = (const float*)d_in[0];
    const float* trg   = (const float*)d_in[1];
    const float* eWih  = (const float*)d_in[2];
    const float* eWhh  = (const float*)d_in[3];
    const float* ebih  = (const float*)d_in[4];
    const float* ebhh  = (const float*)d_in[5];
    const float* dWih  = (const float*)d_in[6];
    const float* dWhh  = (const float*)d_in[7];
    const float* dbih  = (const float*)d_in[8];
    const float* dbhh  = (const float*)d_in[9];
    const float* fcW   = (const float*)d_in[10];
    const float* fcb   = (const float*)d_in[11];
    float* out = (float*)d_out;

    uintptr_t base = (uintptr_t)d_ws;
    size_t off = 0;
    auto alloc = [&](size_t bytes) -> void* {
        void* p = (void*)(base + off);
        off = (off + bytes + 255) & ~(size_t)255;
        return p;
    };
    unsigned* bar = (unsigned*)alloc(8192);
    unsigned short* srcp = (unsigned short*)alloc((size_t)SEQN * 64 * 256 * 2);
    unsigned short* trgp = (unsigned short*)alloc((size_t)64 * 256 * 2);
    float* benc  = (float*)alloc(G4 * 4);
    float* bdec0 = (float*)alloc(G4 * 4);
    float* bcomb = (float*)alloc(G4 * 4);
    unsigned short* fcf    = (unsigned short*)alloc((size_t)256 * 1024 * 2);
    unsigned short* Wencf  = (unsigned short*)alloc((size_t)9216 * 1024 * 2);
    unsigned short* Wdec0f = (unsigned short*)alloc((size_t)9216 * 1024 * 2);
    unsigned short* Wcombf = (unsigned short*)alloc((size_t)8192 * 1024 * 2);
    float* Wcomb32 = (float*)alloc((size_t)G4 * HH * 4);
    unsigned short* hseq   = (unsigned short*)alloc((size_t)512 * SLOT * 2);
    const bool fastok = (off <= ws_size);

    if (fastok) {
        init_persist<<<296, 256, 0, stream>>>(hseq, out, bar);
        prep_src<<<8192, 256, 0, stream>>>(src, srcp, BB * SEQN * DXX);
        prep_trg0<<<32, 256, 0, stream>>>(trg, trgp);
        prep_bias_p<<<16, 256, 0, stream>>>(ebih, ebhh, dbih, dbhh, dWih, fcb,
                                            benc, bdec0, bcomb);
        prep_frag_12<<<2304, 256, 0, stream>>>(eWhh, eWih, Wencf);
        prep_frag_12<<<2304, 256, 0, stream>>>(dWhh, dWih, Wdec0f);
        wcomb_kernel<<<2048, 256, 0, stream>>>(dWhh, dWih, fcW, Wcomb32);
        prep_frag_comb<<<2048, 256, 0, stream>>>(Wcomb32, Wcombf);
        prep_frag_fc<<<64, 256, 0, stream>>>(fcW, fcf);

        persist<<<256, 1024, 0, stream>>>(Wencf, Wdec0f, Wcombf, srcp, trgp,
                                          benc, bdec0, bcomb, hseq, bar);
        fc_batch<<<255, 256, 0, stream>>>(fcf, hseq, fcb, out);
        return;
    }

    // ---- fallback: fp32 per-step path ----
    float* ws  = (float*)d_ws;
    float* h0     = ws;
    float* h1     = ws + 65536;
    float* cF     = ws + 131072;
    float* pred   = ws + 196608;
    float* enc_b  = ws + 204800;
    float* dec_b  = ws + 208896;
    float* bcombF = ws + 212992;
    float* Wcomb  = ws + 217088;
    const bool use_comb = ws_size >= (size_t)(217088 + 4096 * 1024) * sizeof(float);

    init_kernel<<<544, 256, 0, stream>>>(h0, cF, out);
    bias_prep<<<16, 256, 0, stream>>>(ebih, ebhh, dbih, dbhh, dWih, fcb, enc_b, dec_b, bcombF);
    if (use_comb)
        wcomb_kernel<<<2048, 256, 0, stream>>>(dWhh, dWih, fcW, Wcomb);

    float* hc = h0;
    float* hn = h1;
    for (int s = 0; s < SEQN; ++s) {
        step_kernel<<<256, 256, 0, stream>>>(eWhh, eWih, src + s * DXX, SEQN * DXX,
                                             enc_b, hc, cF, hn, 256,
                                             nullptr, nullptr, nullptr, nullptr);
        float* tmp = hc; hc = hn; hn = tmp;
    }
    step_kernel<<<256, 256, 0, stream>>>(dWhh, dWih, trg, TN * DXX,
                                         dec_b, hc, cF, hn, 256,
                                         nullptr, nullptr, nullptr, nullptr);
    { float* tmp = hc; hc = hn; hn = tmp; }
    if (use_comb) {
        for (int tt = 1; tt <= TN - 2; ++tt) {
            step_kernel<<<288, 256, 0, stream>>>(Wcomb, nullptr, nullptr, 0,
                                                 bcombF, hc, cF, hn, 256,
                                                 fcW, fcb, out + (size_t)tt * DXX, nullptr);
            float* tmp = hc; hc = hn; hn = tmp;
        }
    } else {
        for (int tt = 1; tt <= TN - 2; ++tt) {
            step_kernel<<<32, 256, 0, stream>>>(nullptr, nullptr, nullptr, 0,
                                                nullptr, hc, nullptr, nullptr, 0,
                                                fcW, fcb, out + (size_t)tt * DXX, pred);
            step_kernel<<<256, 256, 0, stream>>>(dWhh, dWih, pred, DXX,
                                                 dec_b, hc, cF, hn, 256,
                                                 nullptr, nullptr, nullptr, nullptr);
            float* tmp = hc; hc = hn; hn = tmp;
        }
    }
    step_kernel<<<32, 256, 0, stream>>>(nullptr, nullptr, nullptr, 0,
                                        nullptr, hc, nullptr, nullptr, 0,
                                        fcW, fcb, out + (size_t)(TN - 1) * DXX, nullptr);
}